// Round 1
// baseline (1644.688 us; speedup 1.0000x reference)
//
#include <hip/hip_runtime.h>

// ---------------------------------------------------------------------------
// SetEdgeModel: GNN encoder + 3 SAGE layers + L2-normalize + edge MLP head.
// Round 0: all-fp32 correctness-first implementation.
//   - CSR built per call (count/scan/fill) -> conflict-free wave-per-node mean
//   - generic 64x64 LDS-tiled fp32 GEMM (4x4 microtile), dual-A variant for
//     h@Ws_self + mean@Ws_nei in one pass
//   - fused gather+|hi-hj|/hi*hj feat construction inside the head GEMM1
// Workspace layout (floats), F = 50000*256 = 12.8M:
//   [0,F)=hA  [F,2F)=hB  [2F,3F)=mean  [3F,+)=degf/cnt/cursor/row_start/csr
//   edge phase reuse: z1=[0,2F)  z2=[2F,4F)   (peak ws = 4F floats = 204.8 MB)
// ---------------------------------------------------------------------------

#define NODES 50000
#define EDGES 300000
#define PAIRS 200000

__global__ __launch_bounds__(256) void zero_ints_kernel(int* __restrict__ a, int n) {
  int i = blockIdx.x * 256 + threadIdx.x;
  if (i < n) a[i] = 0;
}

__global__ __launch_bounds__(256) void count_deg_kernel(const int* __restrict__ dst,
                                                        int* __restrict__ cnt) {
  int e = blockIdx.x * 256 + threadIdx.x;
  if (e < EDGES) atomicAdd(&cnt[dst[e]], 1);
}

// single-block exclusive scan over NODES counts; also writes degf = max(cnt,1)
__global__ __launch_bounds__(1024) void scan_kernel(const int* __restrict__ cnt,
                                                    int* __restrict__ row_start,
                                                    float* __restrict__ degf) {
  __shared__ int buf[1024];
  __shared__ int carry_s;
  const int tid = threadIdx.x;
  if (tid == 0) carry_s = 0;
  __syncthreads();
  for (int base = 0; base < NODES; base += 1024) {
    int i = base + tid;
    int v = (i < NODES) ? cnt[i] : 0;
    buf[tid] = v;
    __syncthreads();
    for (int off = 1; off < 1024; off <<= 1) {
      int t = (tid >= off) ? buf[tid - off] : 0;
      __syncthreads();
      buf[tid] += t;
      __syncthreads();
    }
    int incl = buf[tid];
    int carry = carry_s;
    if (i < NODES) {
      row_start[i] = carry + incl - v;
      degf[i] = (float)(v > 0 ? v : 1);
    }
    __syncthreads();
    if (tid == 1023) carry_s = carry + incl;
    __syncthreads();
  }
  if (tid == 0) row_start[NODES] = carry_s;
}

__global__ __launch_bounds__(256) void fill_csr_kernel(const int* __restrict__ src,
                                                       const int* __restrict__ dst,
                                                       const int* __restrict__ row_start,
                                                       int* __restrict__ cursor,
                                                       int* __restrict__ csr) {
  int e = blockIdx.x * 256 + threadIdx.x;
  if (e < EDGES) {
    int d = dst[e];
    int pos = atomicAdd(&cursor[d], 1);
    csr[row_start[d] + pos] = src[e];
  }
}

// wave-per-node segmented mean: mean[n,:] = sum_{e in csr[n]} h[src,:] / deg[n]
__global__ __launch_bounds__(256) void aggregate_kernel(const float* __restrict__ h,
                                                        const int* __restrict__ row_start,
                                                        const int* __restrict__ csr,
                                                        const float* __restrict__ degf,
                                                        float* __restrict__ mean) {
  int wid = threadIdx.x >> 6, lane = threadIdx.x & 63;
  int n = blockIdx.x * 4 + wid;
  if (n >= NODES) return;
  int rs = row_start[n], re = row_start[n + 1];
  float4 acc = {0.f, 0.f, 0.f, 0.f};
  for (int e = rs; e < re; ++e) {
    int s = csr[e];
    float4 v = ((const float4*)(h + (size_t)s * 256))[lane];
    acc.x += v.x; acc.y += v.y; acc.z += v.z; acc.w += v.w;
  }
  float inv = 1.0f / degf[n];
  acc.x *= inv; acc.y *= inv; acc.z *= inv; acc.w *= inv;
  ((float4*)(mean + (size_t)n * 256))[lane] = acc;
}

// generic 64x64 tiled fp32 GEMM: C = act(A@B [+ A2@B2] + bias1 [+ bias2])
// A:[M,K] row-major, B:[K,N] row-major. K%16==0, N%64==0.
template <int RELU, int DUAL>
__global__ __launch_bounds__(256) void gemm_kernel(const float* __restrict__ A,
                                                   const float* __restrict__ B,
                                                   const float* __restrict__ A2,
                                                   const float* __restrict__ B2,
                                                   const float* __restrict__ bias1,
                                                   const float* __restrict__ bias2,
                                                   float* __restrict__ C,
                                                   int M, int N, int K) {
  __shared__ float As[16][68];  // [k][m], +4 pad keeps float4 align & breaks conflicts
  __shared__ float Bs[16][68];  // [k][n]
  const int tid = threadIdx.x;
  const int bm = blockIdx.y * 64;
  const int bn = blockIdx.x * 64;
  const int lr = tid >> 2;            // 0..63 A-tile row
  const int lk = (tid & 3) << 2;      // 0,4,8,12 A-tile k
  const int kb = tid >> 4;            // 0..15 B-tile k row
  const int nq = (tid & 15) << 2;     // B-tile col
  const int tx = tid & 15;
  const int ty = tid >> 4;
  float acc[4][4] = {};

  for (int pass = 0; pass < 1 + DUAL; ++pass) {
    const float* __restrict__ Ap = pass ? A2 : A;
    const float* __restrict__ Bp = pass ? B2 : B;
    for (int k0 = 0; k0 < K; k0 += 16) {
      __syncthreads();
      int ar = bm + lr;
      float4 av = {0.f, 0.f, 0.f, 0.f};
      if (ar < M) av = *(const float4*)(Ap + (size_t)ar * K + k0 + lk);
      As[lk + 0][lr] = av.x;
      As[lk + 1][lr] = av.y;
      As[lk + 2][lr] = av.z;
      As[lk + 3][lr] = av.w;
      *(float4*)&Bs[kb][nq] = *(const float4*)(Bp + (size_t)(k0 + kb) * N + bn + nq);
      __syncthreads();
#pragma unroll
      for (int kk = 0; kk < 16; ++kk) {
        float4 a = *(const float4*)&As[kk][ty << 2];
        float4 b = *(const float4*)&Bs[kk][tx << 2];
        float av4[4] = {a.x, a.y, a.z, a.w};
        float bv4[4] = {b.x, b.y, b.z, b.w};
#pragma unroll
        for (int i = 0; i < 4; ++i)
#pragma unroll
          for (int j = 0; j < 4; ++j) acc[i][j] += av4[i] * bv4[j];
      }
    }
  }

  float4 bsum = *(const float4*)(bias1 + bn + (tx << 2));
  if (DUAL) {
    float4 b2v = *(const float4*)(bias2 + bn + (tx << 2));
    bsum.x += b2v.x; bsum.y += b2v.y; bsum.z += b2v.z; bsum.w += b2v.w;
  }
#pragma unroll
  for (int i = 0; i < 4; ++i) {
    int r = bm + (ty << 2) + i;
    if (r < M) {
      float4 o = {acc[i][0] + bsum.x, acc[i][1] + bsum.y,
                  acc[i][2] + bsum.z, acc[i][3] + bsum.w};
      if (RELU) {
        o.x = fmaxf(o.x, 0.f); o.y = fmaxf(o.y, 0.f);
        o.z = fmaxf(o.z, 0.f); o.w = fmaxf(o.w, 0.f);
      }
      *(float4*)(C + (size_t)r * N + bn + (tx << 2)) = o;
    }
  }
}

// wave-per-row: h = LN(relu(x)) * gamma + beta   (in-place safe, row-local)
__global__ __launch_bounds__(256) void relu_ln_kernel(const float* __restrict__ in,
                                                      float* __restrict__ out,
                                                      const float* __restrict__ gamma,
                                                      const float* __restrict__ beta) {
  int wid = threadIdx.x >> 6, lane = threadIdx.x & 63;
  int row = blockIdx.x * 4 + wid;
  if (row >= NODES) return;
  float4 x = ((const float4*)(in + (size_t)row * 256))[lane];
  float4 r = {fmaxf(x.x, 0.f), fmaxf(x.y, 0.f), fmaxf(x.z, 0.f), fmaxf(x.w, 0.f)};
  float s1 = r.x + r.y + r.z + r.w;
  float s2 = r.x * r.x + r.y * r.y + r.z * r.z + r.w * r.w;
#pragma unroll
  for (int off = 32; off > 0; off >>= 1) {
    s1 += __shfl_down(s1, off);
    s2 += __shfl_down(s2, off);
  }
  s1 = __shfl(s1, 0);
  s2 = __shfl(s2, 0);
  float mu = s1 * (1.f / 256.f);
  float var = fmaxf(s2 * (1.f / 256.f) - mu * mu, 0.f);
  float rstd = rsqrtf(var + 1e-5f);
  float4 g = ((const float4*)gamma)[lane];
  float4 b = ((const float4*)beta)[lane];
  float4 y = {(r.x - mu) * rstd * g.x + b.x, (r.y - mu) * rstd * g.y + b.y,
              (r.z - mu) * rstd * g.z + b.z, (r.w - mu) * rstd * g.w + b.w};
  ((float4*)(out + (size_t)row * 256))[lane] = y;
}

// wave-per-row: H = h / max(||h||_2, 1e-12)
__global__ __launch_bounds__(256) void normalize_kernel(const float* __restrict__ in,
                                                        float* __restrict__ out) {
  int wid = threadIdx.x >> 6, lane = threadIdx.x & 63;
  int row = blockIdx.x * 4 + wid;
  if (row >= NODES) return;
  float4 x = ((const float4*)(in + (size_t)row * 256))[lane];
  float s2 = x.x * x.x + x.y * x.y + x.z * x.z + x.w * x.w;
#pragma unroll
  for (int off = 32; off > 0; off >>= 1) s2 += __shfl_down(s2, off);
  s2 = __shfl(s2, 0);
  float inv = 1.f / fmaxf(sqrtf(s2), 1e-12f);
  float4 y = {x.x * inv, x.y * inv, x.z * inv, x.w * inv};
  ((float4*)(out + (size_t)row * 256))[lane] = y;
}

// head GEMM1 with fused gather + feat construction:
// z1[p,:] = relu(concat(|hi-hj|, hi*hj) @ W1 + b1), BM=64, BN=128, K=512
__global__ __launch_bounds__(256) void feat_gemm_kernel(const float* __restrict__ H,
                                                        const int* __restrict__ i_idx,
                                                        const int* __restrict__ j_idx,
                                                        const float* __restrict__ W1,
                                                        const float* __restrict__ b1,
                                                        float* __restrict__ z1) {
  __shared__ float As[16][68];
  __shared__ float Bs[16][132];
  __shared__ int ii[64], jj[64];
  const int tid = threadIdx.x;
  const int bm = blockIdx.x * 64;
  if (tid < 64) {
    ii[tid] = i_idx[bm + tid];
    jj[tid] = j_idx[bm + tid];
  }
  __syncthreads();
  const int lr = tid >> 2;
  const int lk = (tid & 3) << 2;
  const int kb = tid >> 4;
  const int nq = (tid & 15) << 3;
  const int tx = tid & 15;
  const int ty = tid >> 4;
  float acc[4][8] = {};

  for (int k0 = 0; k0 < 512; k0 += 16) {
    __syncthreads();
    {
      const float* hi = H + (size_t)ii[lr] * 256;
      const float* hj = H + (size_t)jj[lr] * 256;
      int k = k0 + lk;
      float4 a;
      if (k < 256) {
        float4 x = *(const float4*)(hi + k);
        float4 y = *(const float4*)(hj + k);
        a.x = fabsf(x.x - y.x); a.y = fabsf(x.y - y.y);
        a.z = fabsf(x.z - y.z); a.w = fabsf(x.w - y.w);
      } else {
        float4 x = *(const float4*)(hi + k - 256);
        float4 y = *(const float4*)(hj + k - 256);
        a.x = x.x * y.x; a.y = x.y * y.y; a.z = x.z * y.z; a.w = x.w * y.w;
      }
      As[lk + 0][lr] = a.x; As[lk + 1][lr] = a.y;
      As[lk + 2][lr] = a.z; As[lk + 3][lr] = a.w;
    }
    *(float4*)&Bs[kb][nq] = *(const float4*)(W1 + (size_t)(k0 + kb) * 128 + nq);
    *(float4*)&Bs[kb][nq + 4] = *(const float4*)(W1 + (size_t)(k0 + kb) * 128 + nq + 4);
    __syncthreads();
#pragma unroll
    for (int kk = 0; kk < 16; ++kk) {
      float4 a = *(const float4*)&As[kk][ty << 2];
      float4 b0 = *(const float4*)&Bs[kk][tx << 3];
      float4 b1v = *(const float4*)&Bs[kk][(tx << 3) + 4];
      float av4[4] = {a.x, a.y, a.z, a.w};
      float bv8[8] = {b0.x, b0.y, b0.z, b0.w, b1v.x, b1v.y, b1v.z, b1v.w};
#pragma unroll
      for (int i = 0; i < 4; ++i)
#pragma unroll
        for (int j = 0; j < 8; ++j) acc[i][j] += av4[i] * bv8[j];
    }
  }

  float4 bb0 = *(const float4*)(b1 + (tx << 3));
  float4 bb1 = *(const float4*)(b1 + (tx << 3) + 4);
  float bb[8] = {bb0.x, bb0.y, bb0.z, bb0.w, bb1.x, bb1.y, bb1.z, bb1.w};
#pragma unroll
  for (int i = 0; i < 4; ++i) {
    int p = bm + (ty << 2) + i;
    float4 o0 = {fmaxf(acc[i][0] + bb[0], 0.f), fmaxf(acc[i][1] + bb[1], 0.f),
                 fmaxf(acc[i][2] + bb[2], 0.f), fmaxf(acc[i][3] + bb[3], 0.f)};
    float4 o1 = {fmaxf(acc[i][4] + bb[4], 0.f), fmaxf(acc[i][5] + bb[5], 0.f),
                 fmaxf(acc[i][6] + bb[6], 0.f), fmaxf(acc[i][7] + bb[7], 0.f)};
    *(float4*)(z1 + (size_t)p * 128 + (tx << 3)) = o0;
    *(float4*)(z1 + (size_t)p * 128 + (tx << 3) + 4) = o1;
  }
}

// wave-per-row: logits[p] = z2[p,:] @ W3 + b3
__global__ __launch_bounds__(256) void logits_kernel(const float* __restrict__ z2,
                                                     const float* __restrict__ W3,
                                                     const float* __restrict__ b3,
                                                     float* __restrict__ out) {
  __shared__ float w[128];
  if (threadIdx.x < 128) w[threadIdx.x] = W3[threadIdx.x];
  __syncthreads();
  int wid = threadIdx.x >> 6, lane = threadIdx.x & 63;
  int p = blockIdx.x * 4 + wid;
  if (p >= PAIRS) return;
  float2 z = ((const float2*)(z2 + (size_t)p * 128))[lane];
  float s = z.x * w[lane * 2] + z.y * w[lane * 2 + 1];
#pragma unroll
  for (int off = 32; off > 0; off >>= 1) s += __shfl_down(s, off);
  if (lane == 0) out[p] = s + b3[0];
}

extern "C" void kernel_launch(void* const* d_in, const int* in_sizes, int n_in,
                              void* d_out, int out_size, void* d_ws, size_t ws_size,
                              hipStream_t stream) {
  const float* X       = (const float*)d_in[0];
  const int*   edge    = (const int*)d_in[1];
  const int*   i_idx   = (const int*)d_in[2];
  const int*   j_idx   = (const int*)d_in[3];
  const float* W_in    = (const float*)d_in[4];
  const float* b_in    = (const float*)d_in[5];
  const float* Ws_self = (const float*)d_in[6];
  const float* bs_self = (const float*)d_in[7];
  const float* Ws_nei  = (const float*)d_in[8];
  const float* bs_nei  = (const float*)d_in[9];
  const float* gammas  = (const float*)d_in[10];
  const float* betas   = (const float*)d_in[11];
  const float* W1      = (const float*)d_in[12];
  const float* b1      = (const float*)d_in[13];
  const float* W2      = (const float*)d_in[14];
  const float* b2      = (const float*)d_in[15];
  const float* W3      = (const float*)d_in[16];
  const float* b3      = (const float*)d_in[17];

  const size_t F = (size_t)NODES * 256;  // 12.8M floats
  float* ws = (float*)d_ws;
  float* hA   = ws;
  float* hB   = ws + F;
  float* mean = ws + 2 * F;
  float* degf = ws + 3 * F;
  int* cnt       = (int*)(ws + 3 * F + 1 * 50048);
  int* cursor    = (int*)(ws + 3 * F + 2 * 50048);
  int* row_start = (int*)(ws + 3 * F + 3 * 50048);
  int* csr       = (int*)(ws + 3 * F + 4 * 50048);
  float* z1 = ws;          // reuses hA+hB (dead after normalize)
  float* z2 = ws + 2 * F;  // reuses mean+CSR (dead after layers)

  const int* src = edge;          // edge_index[0]
  const int* dst = edge + EDGES;  // edge_index[1]
  float* Hout   = (float*)d_out;
  float* logits = (float*)d_out + F;

  // encoder: hA = relu(X @ W_in + b_in)
  gemm_kernel<1, 0><<<dim3(4, 782), 256, 0, stream>>>(
      X, W_in, nullptr, nullptr, b_in, nullptr, hA, NODES, 256, 480);

  // CSR build
  zero_ints_kernel<<<(2 * 50048 + 255) / 256, 256, 0, stream>>>(cnt, 2 * 50048);
  count_deg_kernel<<<(EDGES + 255) / 256, 256, 0, stream>>>(dst, cnt);
  scan_kernel<<<1, 1024, 0, stream>>>(cnt, row_start, degf);
  fill_csr_kernel<<<(EDGES + 255) / 256, 256, 0, stream>>>(src, dst, row_start, cursor, csr);

  float* hcur = hA;
  float* hnext = hB;
  for (int l = 0; l < 3; ++l) {
    aggregate_kernel<<<NODES / 4, 256, 0, stream>>>(hcur, row_start, csr, degf, mean);
    gemm_kernel<0, 1><<<dim3(4, 782), 256, 0, stream>>>(
        hcur, Ws_self + (size_t)l * 65536, mean, Ws_nei + (size_t)l * 65536,
        bs_self + l * 256, bs_nei + l * 256, hnext, NODES, 256, 256);
    relu_ln_kernel<<<NODES / 4, 256, 0, stream>>>(hnext, hnext, gammas + l * 256,
                                                  betas + l * 256);
    float* t = hcur; hcur = hnext; hnext = t;
  }

  normalize_kernel<<<NODES / 4, 256, 0, stream>>>(hcur, Hout);

  // edge head
  feat_gemm_kernel<<<PAIRS / 64, 256, 0, stream>>>(Hout, i_idx, j_idx, W1, b1, z1);
  gemm_kernel<1, 0><<<dim3(2, PAIRS / 64), 256, 0, stream>>>(
      z1, W2, nullptr, nullptr, b2, nullptr, z2, PAIRS, 128, 128);
  logits_kernel<<<PAIRS / 4, 256, 0, stream>>>(z2, W3, b3, logits);
}

// Round 2
// 771.926 us; speedup vs baseline: 2.1306x; 2.1306x over previous
//
#include <hip/hip_runtime.h>

// ---------------------------------------------------------------------------
// R1: all five GEMMs moved to bf16 MFMA (16x16x32), m97-style structure:
//   128x128 tile, BK=32, global_load_lds width=16 staging, 4 waves x 4x4 tiles.
// Activations kept bf16 end-to-end; fp32 accumulation; LN/normalize fp32 math.
// Weights converted+transposed (B^T) per call. Feat A-tile computed on the fly.
// ---------------------------------------------------------------------------

#define NODES 50000
#define EDGES 300000
#define PAIRS 200000

typedef __attribute__((ext_vector_type(8))) short short8;
typedef __attribute__((ext_vector_type(4))) float f32x4;

__device__ __forceinline__ unsigned short f2bf(float f) {
  unsigned int u = __float_as_uint(f);
  u += 0x7fff + ((u >> 16) & 1);
  return (unsigned short)(u >> 16);
}
__device__ __forceinline__ float bf2f(unsigned short h) {
  return __uint_as_float(((unsigned int)h) << 16);
}

// async global->LDS, 16B/lane; LDS dest must be wave-uniform base (+lane*16 by HW)
__device__ __forceinline__ void glds16(const void* g, void* l) {
  __builtin_amdgcn_global_load_lds(
      (const __attribute__((address_space(1))) unsigned int*)g,
      (__attribute__((address_space(3))) unsigned int*)l, 16, 0, 0);
}

// ---------------- CSR build ----------------

__global__ __launch_bounds__(256) void zero_ints_kernel(int* __restrict__ a, int n) {
  int i = blockIdx.x * 256 + threadIdx.x;
  if (i < n) a[i] = 0;
}

__global__ __launch_bounds__(256) void count_deg_kernel(const int* __restrict__ dst,
                                                        int* __restrict__ cnt) {
  int e = blockIdx.x * 256 + threadIdx.x;
  if (e < EDGES) atomicAdd(&cnt[dst[e]], 1);
}

__global__ __launch_bounds__(1024) void scan_kernel(const int* __restrict__ cnt,
                                                    int* __restrict__ row_start,
                                                    float* __restrict__ degf) {
  __shared__ int buf[1024];
  __shared__ int carry_s;
  const int tid = threadIdx.x;
  if (tid == 0) carry_s = 0;
  __syncthreads();
  for (int base = 0; base < NODES; base += 1024) {
    int i = base + tid;
    int v = (i < NODES) ? cnt[i] : 0;
    buf[tid] = v;
    __syncthreads();
    for (int off = 1; off < 1024; off <<= 1) {
      int t = (tid >= off) ? buf[tid - off] : 0;
      __syncthreads();
      buf[tid] += t;
      __syncthreads();
    }
    int incl = buf[tid];
    int carry = carry_s;
    if (i < NODES) {
      row_start[i] = carry + incl - v;
      degf[i] = (float)(v > 0 ? v : 1);
    }
    __syncthreads();
    if (tid == 1023) carry_s = carry + incl;
    __syncthreads();
  }
  if (tid == 0) row_start[NODES] = carry_s;
}

__global__ __launch_bounds__(256) void fill_csr_kernel(const int* __restrict__ src,
                                                       const int* __restrict__ dst,
                                                       const int* __restrict__ row_start,
                                                       int* __restrict__ cursor,
                                                       int* __restrict__ csr) {
  int e = blockIdx.x * 256 + threadIdx.x;
  if (e < EDGES) {
    int d = dst[e];
    int pos = atomicAdd(&cursor[d], 1);
    csr[row_start[d] + pos] = src[e];
  }
}

// ---------------- conversions ----------------

__global__ __launch_bounds__(256) void convx_kernel(const float* __restrict__ in,
                                                    unsigned short* __restrict__ out,
                                                    int n4) {
  int i = blockIdx.x * 256 + threadIdx.x;
  if (i < n4) {
    float4 v = ((const float4*)in)[i];
    ushort4 o = {f2bf(v.x), f2bf(v.y), f2bf(v.z), f2bf(v.w)};
    ((ushort4*)out)[i] = o;
  }
}

// out[c][r] = bf16(in[r][c]); R,C multiples of 32; batch via blockIdx.z
__global__ __launch_bounds__(256) void tconv_kernel(const float* __restrict__ in,
                                                    unsigned short* __restrict__ out,
                                                    int R, int C) {
  const float* inb = in + (size_t)blockIdx.z * R * C;
  unsigned short* outb = out + (size_t)blockIdx.z * R * C;
  __shared__ float t[32][33];
  int bx = blockIdx.x * 32, by = blockIdx.y * 32;
  int tx = threadIdx.x & 31, ty = threadIdx.x >> 5;
#pragma unroll
  for (int i = ty; i < 32; i += 8) t[i][tx] = inb[(size_t)(by + i) * C + bx + tx];
  __syncthreads();
#pragma unroll
  for (int i = ty; i < 32; i += 8)
    outb[(size_t)(bx + i) * R + by + tx] = f2bf(t[tx][i]);
}

// ---------------- MFMA GEMM ----------------
// C[M,N] = act(A@B [+ A2@B2] + bias1 [+bias2]); A bf16 [M,K] row-major,
// Bt bf16 [N,K] (i.e. B^T). K%32==0, N%128==0. Output bf16.
template <int DUAL, int RELU>
__global__ __launch_bounds__(256) void mfma_gemm(
    const unsigned short* __restrict__ A, const unsigned short* __restrict__ Bt,
    const unsigned short* __restrict__ A2, const unsigned short* __restrict__ B2t,
    const float* __restrict__ bias1, const float* __restrict__ bias2,
    unsigned short* __restrict__ C, int M, int N, int K) {
  __shared__ __attribute__((aligned(16))) unsigned short As[128 * 32];
  __shared__ __attribute__((aligned(16))) unsigned short Bs[128 * 32];
  const int tid = threadIdx.x;
  const int wv = tid >> 6, ln = tid & 63;
  const int lane15 = ln & 15, quad = ln >> 4;
  const int mhalf = wv >> 1, nhalf = wv & 1;
  const int bm = blockIdx.y * 128, bn = blockIdx.x * 128;
  f32x4 acc[4][4] = {};

  for (int pass = 0; pass <= DUAL; ++pass) {
    const unsigned short* __restrict__ Ap = pass ? A2 : A;
    const unsigned short* __restrict__ Bp = pass ? B2t : Bt;
    for (int k0 = 0; k0 < K; k0 += 32) {
      __syncthreads();
#pragma unroll
      for (int q = 0; q < 2; ++q) {
        int L = (q * 4 + wv) * 64 + ln;
        int r = L >> 2, ck = (L & 3) * 8;
        int gr = bm + r;
        if (gr > M - 1) gr = M - 1;
        glds16(Ap + (size_t)gr * K + k0 + ck, (void*)(As + (q * 4 + wv) * 512));
        glds16(Bp + (size_t)(bn + r) * K + k0 + ck, (void*)(Bs + (q * 4 + wv) * 512));
      }
      __syncthreads();
      short8 af[4], bf[4];
#pragma unroll
      for (int t = 0; t < 4; ++t) {
        af[t] = *(const short8*)&As[(mhalf * 64 + t * 16 + lane15) * 32 + quad * 8];
        bf[t] = *(const short8*)&Bs[(nhalf * 64 + t * 16 + lane15) * 32 + quad * 8];
      }
#pragma unroll
      for (int mt = 0; mt < 4; ++mt)
#pragma unroll
        for (int nt = 0; nt < 4; ++nt)
          acc[mt][nt] = __builtin_amdgcn_mfma_f32_16x16x32_bf16(af[mt], bf[nt],
                                                                acc[mt][nt], 0, 0, 0);
    }
  }

  float bsum[4];
#pragma unroll
  for (int nt = 0; nt < 4; ++nt) {
    int col = bn + nhalf * 64 + nt * 16 + lane15;
    bsum[nt] = bias1[col] + (DUAL ? bias2[col] : 0.f);
  }
#pragma unroll
  for (int mt = 0; mt < 4; ++mt) {
    int rb = bm + mhalf * 64 + mt * 16 + quad * 4;
#pragma unroll
    for (int r = 0; r < 4; ++r) {
      int row = rb + r;
      if (row < M) {
#pragma unroll
        for (int nt = 0; nt < 4; ++nt) {
          int col = bn + nhalf * 64 + nt * 16 + lane15;
          float v = acc[mt][nt][r] + bsum[nt];
          if (RELU) v = fmaxf(v, 0.f);
          C[(size_t)row * N + col] = f2bf(v);
        }
      }
    }
  }
}

// feat GEMM: z1[p,:] = relu(concat(|hi-hj|, hi*hj) @ W1 + b1); A computed on
// the fly from gathered bf16 H rows. BM=128, BN=N=128, K=512.
__global__ __launch_bounds__(256) void feat_mfma_kernel(
    const unsigned short* __restrict__ Hb, const int* __restrict__ i_idx,
    const int* __restrict__ j_idx, const unsigned short* __restrict__ W1t,
    const float* __restrict__ b1, unsigned short* __restrict__ z1) {
  __shared__ __attribute__((aligned(16))) unsigned short As[128 * 32];
  __shared__ __attribute__((aligned(16))) unsigned short Bs[128 * 32];
  __shared__ int ii[128], jj[128];
  const int tid = threadIdx.x;
  const int wv = tid >> 6, ln = tid & 63;
  const int lane15 = ln & 15, quad = ln >> 4;
  const int mhalf = wv >> 1, nhalf = wv & 1;
  const int bm = blockIdx.x * 128;
  if (tid < 128) {
    int p = bm + tid;
    if (p > PAIRS - 1) p = PAIRS - 1;
    ii[tid] = i_idx[p];
    jj[tid] = j_idx[p];
  }
  f32x4 acc[4][4] = {};
  const int ar = tid >> 1;        // staging row 0..127
  const int ak = (tid & 1) * 16;  // k sub-chunk within BK=32

  for (int k0 = 0; k0 < 512; k0 += 32) {
    __syncthreads();  // also publishes ii/jj on first iteration
#pragma unroll
    for (int q = 0; q < 2; ++q) {
      int L = (q * 4 + wv) * 64 + ln;
      int r = L >> 2, ck = (L & 3) * 8;
      glds16(W1t + (size_t)r * 512 + k0 + ck, (void*)(Bs + (q * 4 + wv) * 512));
    }
    {
      int kk = k0 + ak;    // absolute k in [0,512)
      int kc = kk & 255;   // k within an H row
      const unsigned short* hi = Hb + (size_t)ii[ar] * 256 + kc;
      const unsigned short* hj = Hb + (size_t)jj[ar] * 256 + kc;
      union U { uint4 v; unsigned short s[8]; };
      U a0, a1, c0, c1;
      a0.v = *(const uint4*)(hi);
      a1.v = *(const uint4*)(hi + 8);
      c0.v = *(const uint4*)(hj);
      c1.v = *(const uint4*)(hj + 8);
      __attribute__((aligned(16))) unsigned short outv[16];
      const bool isabs = kk < 256;
#pragma unroll
      for (int e = 0; e < 8; ++e) {
        float x = bf2f(a0.s[e]), y = bf2f(c0.s[e]);
        outv[e] = f2bf(isabs ? fabsf(x - y) : x * y);
      }
#pragma unroll
      for (int e = 0; e < 8; ++e) {
        float x = bf2f(a1.s[e]), y = bf2f(c1.s[e]);
        outv[8 + e] = f2bf(isabs ? fabsf(x - y) : x * y);
      }
      *(short8*)&As[ar * 32 + ak] = *(short8*)&outv[0];
      *(short8*)&As[ar * 32 + ak + 8] = *(short8*)&outv[8];
    }
    __syncthreads();
    short8 af[4], bf[4];
#pragma unroll
    for (int t = 0; t < 4; ++t) {
      af[t] = *(const short8*)&As[(mhalf * 64 + t * 16 + lane15) * 32 + quad * 8];
      bf[t] = *(const short8*)&Bs[(nhalf * 64 + t * 16 + lane15) * 32 + quad * 8];
    }
#pragma unroll
    for (int mt = 0; mt < 4; ++mt)
#pragma unroll
      for (int nt = 0; nt < 4; ++nt)
        acc[mt][nt] = __builtin_amdgcn_mfma_f32_16x16x32_bf16(af[mt], bf[nt],
                                                              acc[mt][nt], 0, 0, 0);
  }

  float bsum[4];
#pragma unroll
  for (int nt = 0; nt < 4; ++nt)
    bsum[nt] = b1[nhalf * 64 + nt * 16 + lane15];
#pragma unroll
  for (int mt = 0; mt < 4; ++mt) {
    int rb = bm + mhalf * 64 + mt * 16 + quad * 4;
#pragma unroll
    for (int r = 0; r < 4; ++r) {
      int p = rb + r;
      if (p < PAIRS) {
#pragma unroll
        for (int nt = 0; nt < 4; ++nt) {
          int col = nhalf * 64 + nt * 16 + lane15;
          float v = fmaxf(acc[mt][nt][r] + bsum[nt], 0.f);
          z1[(size_t)p * 128 + col] = f2bf(v);
        }
      }
    }
  }
}

// ---------------- graph aggregate + row-wise ops (bf16 activations) ----------

__global__ __launch_bounds__(256) void aggregate_kernel(
    const unsigned short* __restrict__ h, const int* __restrict__ row_start,
    const int* __restrict__ csr, const float* __restrict__ degf,
    unsigned short* __restrict__ mean) {
  int wid = threadIdx.x >> 6, lane = threadIdx.x & 63;
  int n = blockIdx.x * 4 + wid;
  if (n >= NODES) return;
  int rs = row_start[n], re = row_start[n + 1];
  float a0 = 0.f, a1 = 0.f, a2 = 0.f, a3 = 0.f;
  for (int e = rs; e < re; ++e) {
    int s = csr[e];
    ushort4 v = *(const ushort4*)(h + (size_t)s * 256 + lane * 4);
    a0 += bf2f(v.x); a1 += bf2f(v.y); a2 += bf2f(v.z); a3 += bf2f(v.w);
  }
  float inv = 1.0f / degf[n];
  ushort4 o = {f2bf(a0 * inv), f2bf(a1 * inv), f2bf(a2 * inv), f2bf(a3 * inv)};
  *(ushort4*)(mean + (size_t)n * 256 + lane * 4) = o;
}

// LN only (relu already applied in GEMM epilogue); in-place on bf16 rows
__global__ __launch_bounds__(256) void ln_kernel(unsigned short* __restrict__ h,
                                                 const float* __restrict__ gamma,
                                                 const float* __restrict__ beta) {
  int wid = threadIdx.x >> 6, lane = threadIdx.x & 63;
  int row = blockIdx.x * 4 + wid;
  if (row >= NODES) return;
  ushort4 v = *(const ushort4*)(h + (size_t)row * 256 + lane * 4);
  float x0 = bf2f(v.x), x1 = bf2f(v.y), x2 = bf2f(v.z), x3 = bf2f(v.w);
  float s1 = x0 + x1 + x2 + x3;
  float s2 = x0 * x0 + x1 * x1 + x2 * x2 + x3 * x3;
#pragma unroll
  for (int off = 32; off > 0; off >>= 1) {
    s1 += __shfl_down(s1, off);
    s2 += __shfl_down(s2, off);
  }
  s1 = __shfl(s1, 0);
  s2 = __shfl(s2, 0);
  float mu = s1 * (1.f / 256.f);
  float var = fmaxf(s2 * (1.f / 256.f) - mu * mu, 0.f);
  float rstd = rsqrtf(var + 1e-5f);
  float4 g = ((const float4*)gamma)[lane];
  float4 b = ((const float4*)beta)[lane];
  ushort4 o = {f2bf((x0 - mu) * rstd * g.x + b.x), f2bf((x1 - mu) * rstd * g.y + b.y),
               f2bf((x2 - mu) * rstd * g.z + b.z), f2bf((x3 - mu) * rstd * g.w + b.w)};
  *(ushort4*)(h + (size_t)row * 256 + lane * 4) = o;
}

// H = h/||h||; writes fp32 Hout (d_out) and bf16 Hb (for the edge head)
__global__ __launch_bounds__(256) void normalize_kernel(
    const unsigned short* __restrict__ in, float* __restrict__ Hout,
    unsigned short* __restrict__ Hb) {
  int wid = threadIdx.x >> 6, lane = threadIdx.x & 63;
  int row = blockIdx.x * 4 + wid;
  if (row >= NODES) return;
  ushort4 v = *(const ushort4*)(in + (size_t)row * 256 + lane * 4);
  float x0 = bf2f(v.x), x1 = bf2f(v.y), x2 = bf2f(v.z), x3 = bf2f(v.w);
  float s2 = x0 * x0 + x1 * x1 + x2 * x2 + x3 * x3;
#pragma unroll
  for (int off = 32; off > 0; off >>= 1) s2 += __shfl_down(s2, off);
  s2 = __shfl(s2, 0);
  float inv = 1.f / fmaxf(sqrtf(s2), 1e-12f);
  float y0 = x0 * inv, y1 = x1 * inv, y2 = x2 * inv, y3 = x3 * inv;
  float4 o = {y0, y1, y2, y3};
  ((float4*)(Hout + (size_t)row * 256))[lane] = o;
  ushort4 ob = {f2bf(y0), f2bf(y1), f2bf(y2), f2bf(y3)};
  *(ushort4*)(Hb + (size_t)row * 256 + lane * 4) = ob;
}

__global__ __launch_bounds__(256) void logits_kernel(const unsigned short* __restrict__ z2,
                                                     const float* __restrict__ W3,
                                                     const float* __restrict__ b3,
                                                     float* __restrict__ out) {
  __shared__ float w[128];
  if (threadIdx.x < 128) w[threadIdx.x] = W3[threadIdx.x];
  __syncthreads();
  int wid = threadIdx.x >> 6, lane = threadIdx.x & 63;
  int p = blockIdx.x * 4 + wid;
  if (p >= PAIRS) return;
  ushort2 z = *(const ushort2*)(z2 + (size_t)p * 128 + lane * 2);
  float s = bf2f(z.x) * w[lane * 2] + bf2f(z.y) * w[lane * 2 + 1];
#pragma unroll
  for (int off = 32; off > 0; off >>= 1) s += __shfl_down(s, off);
  if (lane == 0) out[p] = s + b3[0];
}

// ---------------- host ----------------

extern "C" void kernel_launch(void* const* d_in, const int* in_sizes, int n_in,
                              void* d_out, int out_size, void* d_ws, size_t ws_size,
                              hipStream_t stream) {
  const float* X       = (const float*)d_in[0];
  const int*   edge    = (const int*)d_in[1];
  const int*   i_idx   = (const int*)d_in[2];
  const int*   j_idx   = (const int*)d_in[3];
  const float* W_in    = (const float*)d_in[4];
  const float* b_in    = (const float*)d_in[5];
  const float* Ws_self = (const float*)d_in[6];
  const float* bs_self = (const float*)d_in[7];
  const float* Ws_nei  = (const float*)d_in[8];
  const float* bs_nei  = (const float*)d_in[9];
  const float* gammas  = (const float*)d_in[10];
  const float* betas   = (const float*)d_in[11];
  const float* W1      = (const float*)d_in[12];
  const float* b1      = (const float*)d_in[13];
  const float* W2      = (const float*)d_in[14];
  const float* b2      = (const float*)d_in[15];
  const float* W3      = (const float*)d_in[16];
  const float* b3      = (const float*)d_in[17];

  char* w = (char*)d_ws;
  size_t off = 0;
  auto alloc = [&](size_t bytes) {
    char* p = w + off;
    off += (bytes + 255) & ~(size_t)255;
    return p;
  };
  unsigned short* hA   = (unsigned short*)alloc((size_t)NODES * 256 * 2);  // 25.6MB
  unsigned short* hB   = (unsigned short*)alloc((size_t)NODES * 256 * 2);
  unsigned short* mean = (unsigned short*)alloc((size_t)NODES * 256 * 2);
  unsigned short* Hb   = (unsigned short*)alloc((size_t)NODES * 256 * 2);
  float* degf     = (float*)alloc((size_t)NODES * 4);
  int* cnt        = (int*)alloc((size_t)2 * NODES * 4);
  int* cursor     = cnt + NODES;
  int* row_start  = (int*)alloc((size_t)(NODES + 1) * 4);
  int* csr        = (int*)alloc((size_t)EDGES * 4);
  unsigned short* WinT   = (unsigned short*)alloc((size_t)480 * 256 * 2);
  unsigned short* WselfT = (unsigned short*)alloc((size_t)3 * 256 * 256 * 2);
  unsigned short* WneiT  = (unsigned short*)alloc((size_t)3 * 256 * 256 * 2);
  unsigned short* W1T    = (unsigned short*)alloc((size_t)512 * 128 * 2);
  unsigned short* W2T    = (unsigned short*)alloc((size_t)128 * 128 * 2);
  unsigned short* Xb     = (unsigned short*)alloc((size_t)NODES * 480 * 2);  // 48MB
  // dead-region reuse for the edge head:
  unsigned short* z1 = hA;    // 51.2MB over hA+hB (dead after normalize)
  unsigned short* z2 = mean;  // 51.2MB over mean+Hb (Hb dead after feat gemm)

  const int* src = edge;
  const int* dst = edge + EDGES;
  float* Hout   = (float*)d_out;
  float* logits = (float*)d_out + (size_t)NODES * 256;

  // conversions
  convx_kernel<<<(NODES * 480 / 4 + 255) / 256, 256, 0, stream>>>(X, Xb, NODES * 480 / 4);
  tconv_kernel<<<dim3(8, 15, 1), 256, 0, stream>>>(W_in, WinT, 480, 256);
  tconv_kernel<<<dim3(8, 8, 3), 256, 0, stream>>>(Ws_self, WselfT, 256, 256);
  tconv_kernel<<<dim3(8, 8, 3), 256, 0, stream>>>(Ws_nei, WneiT, 256, 256);
  tconv_kernel<<<dim3(4, 16, 1), 256, 0, stream>>>(W1, W1T, 512, 128);
  tconv_kernel<<<dim3(4, 4, 1), 256, 0, stream>>>(W2, W2T, 128, 128);

  // CSR build
  zero_ints_kernel<<<(2 * NODES + 255) / 256, 256, 0, stream>>>(cnt, 2 * NODES);
  count_deg_kernel<<<(EDGES + 255) / 256, 256, 0, stream>>>(dst, cnt);
  scan_kernel<<<1, 1024, 0, stream>>>(cnt, row_start, degf);
  fill_csr_kernel<<<(EDGES + 255) / 256, 256, 0, stream>>>(src, dst, row_start, cursor, csr);

  // encoder: hA = relu(Xb @ W_in + b_in)
  mfma_gemm<0, 1><<<dim3(2, 391), 256, 0, stream>>>(
      Xb, WinT, nullptr, nullptr, b_in, nullptr, hA, NODES, 256, 480);

  unsigned short* hcur = hA;
  unsigned short* hnext = hB;
  for (int l = 0; l < 3; ++l) {
    aggregate_kernel<<<NODES / 4, 256, 0, stream>>>(hcur, row_start, csr, degf, mean);
    mfma_gemm<1, 1><<<dim3(2, 391), 256, 0, stream>>>(
        hcur, WselfT + (size_t)l * 65536, mean, WneiT + (size_t)l * 65536,
        bs_self + l * 256, bs_nei + l * 256, hnext, NODES, 256, 256);
    ln_kernel<<<NODES / 4, 256, 0, stream>>>(hnext, gammas + l * 256, betas + l * 256);
    unsigned short* t = hcur; hcur = hnext; hnext = t;
  }

  normalize_kernel<<<NODES / 4, 256, 0, stream>>>(hcur, Hout, Hb);

  // edge head
  feat_mfma_kernel<<<(PAIRS + 127) / 128, 256, 0, stream>>>(Hb, i_idx, j_idx, W1T, b1, z1);
  mfma_gemm<0, 1><<<dim3(1, (PAIRS + 127) / 128), 256, 0, stream>>>(
      z1, W2T, nullptr, nullptr, b2, nullptr, z2, PAIRS, 128, 128);
  logits_kernel<<<PAIRS / 4, 256, 0, stream>>>(z2, W3, b3, logits);
}

// Round 3
// 662.465 us; speedup vs baseline: 2.4827x; 1.1652x over previous
//
#include <hip/hip_runtime.h>

// ---------------------------------------------------------------------------
// R2: (a) feat GEMM restructured to read each gathered H row ONCE (dual A-tile
//     |hi-hj| / hi*hj per K-iter, 2 MFMAs per read);
//     (b) layer GEMMs use BN=256 (full rows per block) with LayerNorm fused in
//     the epilogue; layer 3 also fuses the L2-normalize (fp32 Hout + bf16 Hb);
//     (c) z2 GEMM fuses the W3 dot -> logits (z2 never materialized);
//     (d) aggregate 2-edge unroll.
// ---------------------------------------------------------------------------

#define NODES 50000
#define EDGES 300000
#define PAIRS 200000

typedef __attribute__((ext_vector_type(8))) short short8;
typedef __attribute__((ext_vector_type(4))) float f32x4;

__device__ __forceinline__ unsigned short f2bf(float f) {
  unsigned int u = __float_as_uint(f);
  u += 0x7fff + ((u >> 16) & 1);
  return (unsigned short)(u >> 16);
}
__device__ __forceinline__ float bf2f(unsigned short h) {
  return __uint_as_float(((unsigned int)h) << 16);
}

__device__ __forceinline__ void glds16(const void* g, void* l) {
  __builtin_amdgcn_global_load_lds(
      (const __attribute__((address_space(1))) unsigned int*)g,
      (__attribute__((address_space(3))) unsigned int*)l, 16, 0, 0);
}

// ---------------- CSR build ----------------

__global__ __launch_bounds__(256) void zero_ints_kernel(int* __restrict__ a, int n) {
  int i = blockIdx.x * 256 + threadIdx.x;
  if (i < n) a[i] = 0;
}

__global__ __launch_bounds__(256) void count_deg_kernel(const int* __restrict__ dst,
                                                        int* __restrict__ cnt) {
  int e = blockIdx.x * 256 + threadIdx.x;
  if (e < EDGES) atomicAdd(&cnt[dst[e]], 1);
}

__global__ __launch_bounds__(1024) void scan_kernel(const int* __restrict__ cnt,
                                                    int* __restrict__ row_start,
                                                    float* __restrict__ degf) {
  __shared__ int buf[1024];
  __shared__ int carry_s;
  const int tid = threadIdx.x;
  if (tid == 0) carry_s = 0;
  __syncthreads();
  for (int base = 0; base < NODES; base += 1024) {
    int i = base + tid;
    int v = (i < NODES) ? cnt[i] : 0;
    buf[tid] = v;
    __syncthreads();
    for (int off = 1; off < 1024; off <<= 1) {
      int t = (tid >= off) ? buf[tid - off] : 0;
      __syncthreads();
      buf[tid] += t;
      __syncthreads();
    }
    int incl = buf[tid];
    int carry = carry_s;
    if (i < NODES) {
      row_start[i] = carry + incl - v;
      degf[i] = (float)(v > 0 ? v : 1);
    }
    __syncthreads();
    if (tid == 1023) carry_s = carry + incl;
    __syncthreads();
  }
  if (tid == 0) row_start[NODES] = carry_s;
}

__global__ __launch_bounds__(256) void fill_csr_kernel(const int* __restrict__ src,
                                                       const int* __restrict__ dst,
                                                       const int* __restrict__ row_start,
                                                       int* __restrict__ cursor,
                                                       int* __restrict__ csr) {
  int e = blockIdx.x * 256 + threadIdx.x;
  if (e < EDGES) {
    int d = dst[e];
    int pos = atomicAdd(&cursor[d], 1);
    csr[row_start[d] + pos] = src[e];
  }
}

// ---------------- conversions ----------------

__global__ __launch_bounds__(256) void convx_kernel(const float* __restrict__ in,
                                                    unsigned short* __restrict__ out,
                                                    int n4) {
  int i = blockIdx.x * 256 + threadIdx.x;
  if (i < n4) {
    float4 v = ((const float4*)in)[i];
    ushort4 o = {f2bf(v.x), f2bf(v.y), f2bf(v.z), f2bf(v.w)};
    ((ushort4*)out)[i] = o;
  }
}

// out[c][r] = bf16(in[r][c]); R,C multiples of 32
__global__ __launch_bounds__(256) void tconv_kernel(const float* __restrict__ in,
                                                    unsigned short* __restrict__ out,
                                                    int R, int C) {
  const float* inb = in + (size_t)blockIdx.z * R * C;
  unsigned short* outb = out + (size_t)blockIdx.z * R * C;
  __shared__ float t[32][33];
  int bx = blockIdx.x * 32, by = blockIdx.y * 32;
  int tx = threadIdx.x & 31, ty = threadIdx.x >> 5;
#pragma unroll
  for (int i = ty; i < 32; i += 8) t[i][tx] = inb[(size_t)(by + i) * C + bx + tx];
  __syncthreads();
#pragma unroll
  for (int i = ty; i < 32; i += 8)
    outb[(size_t)(bx + i) * R + by + tx] = f2bf(t[tx][i]);
}

// ---------------- fused MFMA GEMM, N=256, BM=64, full rows per block -------
// EPI: 0 = relu->bf16 store; 1 = relu+LN->bf16; 2 = relu+LN+L2norm->f32+bf16
template <int DUAL, int EPI>
__global__ __launch_bounds__(256) void mfma_fused(
    const unsigned short* __restrict__ A, const unsigned short* __restrict__ Bt,
    const unsigned short* __restrict__ A2, const unsigned short* __restrict__ B2t,
    const float* __restrict__ bias1, const float* __restrict__ bias2,
    const float* __restrict__ gamma, const float* __restrict__ beta,
    unsigned short* __restrict__ Cb, float* __restrict__ Cf, int M, int K) {
  __shared__ __attribute__((aligned(16))) unsigned short sm[320 * 32];  // A:64, B:256
  __shared__ float red1[4][64], red2[4][64];
  __shared__ float mu_s[64], rs_s[64];
  const int tid = threadIdx.x;
  const int wv = tid >> 6, ln = tid & 63;
  const int lane15 = ln & 15, quad = ln >> 4;
  const int bm = blockIdx.x * 64;
  unsigned short* Bsm = sm + 64 * 32;
  f32x4 acc[4][4] = {};

  for (int pass = 0; pass <= DUAL; ++pass) {
    const unsigned short* __restrict__ Ap = pass ? A2 : A;
    const unsigned short* __restrict__ Bp = pass ? B2t : Bt;
    for (int k0 = 0; k0 < K; k0 += 32) {
      __syncthreads();
#pragma unroll
      for (int q = 0; q < 5; ++q) {
        int L = q * 256 + tid;
        int r = L >> 2, ck = (L & 3) * 8;
        const unsigned short* gp;
        if (r < 64) {
          int gr = bm + r;
          if (gr > M - 1) gr = M - 1;
          gp = Ap + (size_t)gr * K + k0 + ck;
        } else {
          gp = Bp + (size_t)(r - 64) * K + k0 + ck;
        }
        glds16(gp, sm + (size_t)(q * 256 + (tid & 192)) * 8);
      }
      __syncthreads();
      short8 af[4], bfr[4];
#pragma unroll
      for (int t = 0; t < 4; ++t) {
        af[t] = *(const short8*)&sm[(t * 16 + lane15) * 32 + quad * 8];
        bfr[t] = *(const short8*)&Bsm[(wv * 64 + t * 16 + lane15) * 32 + quad * 8];
      }
#pragma unroll
      for (int mt = 0; mt < 4; ++mt)
#pragma unroll
        for (int nt = 0; nt < 4; ++nt)
          acc[mt][nt] = __builtin_amdgcn_mfma_f32_16x16x32_bf16(af[mt], bfr[nt],
                                                                acc[mt][nt], 0, 0, 0);
    }
  }

  // epilogue
  float bsum[4];
#pragma unroll
  for (int nt = 0; nt < 4; ++nt) {
    int col = wv * 64 + nt * 16 + lane15;
    bsum[nt] = bias1[col] + (DUAL ? bias2[col] : 0.f);
  }
  float vv[4][4][4];
#pragma unroll
  for (int mt = 0; mt < 4; ++mt)
#pragma unroll
    for (int nt = 0; nt < 4; ++nt)
#pragma unroll
      for (int r = 0; r < 4; ++r)
        vv[mt][nt][r] = fmaxf(acc[mt][nt][r] + bsum[nt], 0.f);

  if (EPI == 0) {
#pragma unroll
    for (int mt = 0; mt < 4; ++mt)
#pragma unroll
      for (int r = 0; r < 4; ++r) {
        int row = bm + mt * 16 + quad * 4 + r;
        if (row < M) {
#pragma unroll
          for (int nt = 0; nt < 4; ++nt)
            Cb[(size_t)row * 256 + wv * 64 + nt * 16 + lane15] = f2bf(vv[mt][nt][r]);
        }
      }
    return;
  }

  // ---- LayerNorm over the full 256-col row ----
  float s1[4][4], s2[4][4];
#pragma unroll
  for (int mt = 0; mt < 4; ++mt)
#pragma unroll
    for (int r = 0; r < 4; ++r) {
      float a = 0.f, b = 0.f;
#pragma unroll
      for (int nt = 0; nt < 4; ++nt) {
        a += vv[mt][nt][r];
        b += vv[mt][nt][r] * vv[mt][nt][r];
      }
      s1[mt][r] = a;
      s2[mt][r] = b;
    }
#pragma unroll
  for (int st = 1; st < 16; st <<= 1)
#pragma unroll
    for (int mt = 0; mt < 4; ++mt)
#pragma unroll
      for (int r = 0; r < 4; ++r) {
        s1[mt][r] += __shfl_xor(s1[mt][r], st, 64);
        s2[mt][r] += __shfl_xor(s2[mt][r], st, 64);
      }
  if (lane15 == 0) {
#pragma unroll
    for (int mt = 0; mt < 4; ++mt)
#pragma unroll
      for (int r = 0; r < 4; ++r) {
        red1[wv][mt * 16 + quad * 4 + r] = s1[mt][r];
        red2[wv][mt * 16 + quad * 4 + r] = s2[mt][r];
      }
  }
  __syncthreads();
  if (tid < 64) {
    float a = red1[0][tid] + red1[1][tid] + red1[2][tid] + red1[3][tid];
    float b = red2[0][tid] + red2[1][tid] + red2[2][tid] + red2[3][tid];
    float mu = a * (1.f / 256.f);
    float var = fmaxf(b * (1.f / 256.f) - mu * mu, 0.f);
    mu_s[tid] = mu;
    rs_s[tid] = rsqrtf(var + 1e-5f);
  }
  __syncthreads();
  float gg[4], bb[4];
#pragma unroll
  for (int nt = 0; nt < 4; ++nt) {
    int col = wv * 64 + nt * 16 + lane15;
    gg[nt] = gamma[col];
    bb[nt] = beta[col];
  }
#pragma unroll
  for (int mt = 0; mt < 4; ++mt)
#pragma unroll
    for (int r = 0; r < 4; ++r) {
      int rowl = mt * 16 + quad * 4 + r;
      float mu = mu_s[rowl], rstd = rs_s[rowl];
#pragma unroll
      for (int nt = 0; nt < 4; ++nt)
        vv[mt][nt][r] = (vv[mt][nt][r] - mu) * rstd * gg[nt] + bb[nt];
    }

  if (EPI == 1) {
#pragma unroll
    for (int mt = 0; mt < 4; ++mt)
#pragma unroll
      for (int r = 0; r < 4; ++r) {
        int row = bm + mt * 16 + quad * 4 + r;
        if (row < M) {
#pragma unroll
          for (int nt = 0; nt < 4; ++nt)
            Cb[(size_t)row * 256 + wv * 64 + nt * 16 + lane15] = f2bf(vv[mt][nt][r]);
        }
      }
    return;
  }

  // ---- EPI==2: L2 normalize the LN output; store f32 Cf and bf16 Cb ----
  __syncthreads();  // red1 reuse
#pragma unroll
  for (int mt = 0; mt < 4; ++mt)
#pragma unroll
    for (int r = 0; r < 4; ++r) {
      float b = 0.f;
#pragma unroll
      for (int nt = 0; nt < 4; ++nt) b += vv[mt][nt][r] * vv[mt][nt][r];
      s2[mt][r] = b;
    }
#pragma unroll
  for (int st = 1; st < 16; st <<= 1)
#pragma unroll
    for (int mt = 0; mt < 4; ++mt)
#pragma unroll
      for (int r = 0; r < 4; ++r) s2[mt][r] += __shfl_xor(s2[mt][r], st, 64);
  if (lane15 == 0) {
#pragma unroll
    for (int mt = 0; mt < 4; ++mt)
#pragma unroll
      for (int r = 0; r < 4; ++r) red1[wv][mt * 16 + quad * 4 + r] = s2[mt][r];
  }
  __syncthreads();
  if (tid < 64) {
    float b = red1[0][tid] + red1[1][tid] + red1[2][tid] + red1[3][tid];
    mu_s[tid] = 1.f / fmaxf(sqrtf(b), 1e-12f);
  }
  __syncthreads();
#pragma unroll
  for (int mt = 0; mt < 4; ++mt)
#pragma unroll
    for (int r = 0; r < 4; ++r) {
      int rowl = mt * 16 + quad * 4 + r;
      int row = bm + rowl;
      float inv = mu_s[rowl];
      if (row < M) {
#pragma unroll
        for (int nt = 0; nt < 4; ++nt) {
          float y = vv[mt][nt][r] * inv;
          size_t idx = (size_t)row * 256 + wv * 64 + nt * 16 + lane15;
          Cf[idx] = y;
          Cb[idx] = f2bf(y);
        }
      }
    }
}

// ---------------- feat GEMM: single-read dual A-tile -----------------------
// z1[p,:] = relu(concat(|hi-hj|, hi*hj) @ W1 + b1); BM=128, N=128, K=512
// K-loop over 256 with two A-tiles (abs, prod) and two W1 k-slices per iter.
__global__ __launch_bounds__(256) void feat_mfma_kernel(
    const unsigned short* __restrict__ Hb, const int* __restrict__ i_idx,
    const int* __restrict__ j_idx, const unsigned short* __restrict__ W1t,
    const float* __restrict__ b1, unsigned short* __restrict__ z1) {
  __shared__ __attribute__((aligned(16))) unsigned short Aabs[128 * 32];
  __shared__ __attribute__((aligned(16))) unsigned short Aprd[128 * 32];
  __shared__ __attribute__((aligned(16))) unsigned short Blo[128 * 32];
  __shared__ __attribute__((aligned(16))) unsigned short Bhi[128 * 32];
  __shared__ int ii[128], jj[128];
  const int tid = threadIdx.x;
  const int wv = tid >> 6, ln = tid & 63;
  const int lane15 = ln & 15, quad = ln >> 4;
  const int mhalf = wv >> 1, nhalf = wv & 1;
  const int bm = blockIdx.x * 128;
  if (tid < 128) {
    int p = bm + tid;
    if (p > PAIRS - 1) p = PAIRS - 1;
    ii[tid] = i_idx[p];
    jj[tid] = j_idx[p];
  }
  f32x4 acc[4][4] = {};
  const int ar = tid >> 1;
  const int ak = (tid & 1) * 16;

  for (int k0 = 0; k0 < 256; k0 += 32) {
    __syncthreads();
#pragma unroll
    for (int q = 0; q < 2; ++q) {
      int L = q * 256 + tid;
      int r = L >> 2, ck = (L & 3) * 8;
      glds16(W1t + (size_t)r * 512 + k0 + ck,
             Blo + (size_t)(q * 256 + (tid & 192)) * 8);
      glds16(W1t + (size_t)r * 512 + 256 + k0 + ck,
             Bhi + (size_t)(q * 256 + (tid & 192)) * 8);
    }
    {
      int kk = k0 + ak;
      const unsigned short* hi = Hb + (size_t)ii[ar] * 256 + kk;
      const unsigned short* hj = Hb + (size_t)jj[ar] * 256 + kk;
      union U { uint4 v; unsigned short s[8]; };
      U a0, a1, c0, c1;
      a0.v = *(const uint4*)(hi);
      a1.v = *(const uint4*)(hi + 8);
      c0.v = *(const uint4*)(hj);
      c1.v = *(const uint4*)(hj + 8);
      __attribute__((aligned(16))) unsigned short oabs[16], oprd[16];
#pragma unroll
      for (int e = 0; e < 8; ++e) {
        float x = bf2f(a0.s[e]), y = bf2f(c0.s[e]);
        oabs[e] = f2bf(fabsf(x - y));
        oprd[e] = f2bf(x * y);
      }
#pragma unroll
      for (int e = 0; e < 8; ++e) {
        float x = bf2f(a1.s[e]), y = bf2f(c1.s[e]);
        oabs[8 + e] = f2bf(fabsf(x - y));
        oprd[8 + e] = f2bf(x * y);
      }
      *(short8*)&Aabs[ar * 32 + ak] = *(short8*)&oabs[0];
      *(short8*)&Aabs[ar * 32 + ak + 8] = *(short8*)&oabs[8];
      *(short8*)&Aprd[ar * 32 + ak] = *(short8*)&oprd[0];
      *(short8*)&Aprd[ar * 32 + ak + 8] = *(short8*)&oprd[8];
    }
    __syncthreads();
    short8 aA[4], aP[4], bL[4], bH[4];
#pragma unroll
    for (int t = 0; t < 4; ++t) {
      int arow = (mhalf * 64 + t * 16 + lane15) * 32 + quad * 8;
      int brow = (nhalf * 64 + t * 16 + lane15) * 32 + quad * 8;
      aA[t] = *(const short8*)&Aabs[arow];
      aP[t] = *(const short8*)&Aprd[arow];
      bL[t] = *(const short8*)&Blo[brow];
      bH[t] = *(const short8*)&Bhi[brow];
    }
#pragma unroll
    for (int mt = 0; mt < 4; ++mt)
#pragma unroll
      for (int nt = 0; nt < 4; ++nt) {
        acc[mt][nt] = __builtin_amdgcn_mfma_f32_16x16x32_bf16(aA[mt], bL[nt],
                                                              acc[mt][nt], 0, 0, 0);
        acc[mt][nt] = __builtin_amdgcn_mfma_f32_16x16x32_bf16(aP[mt], bH[nt],
                                                              acc[mt][nt], 0, 0, 0);
      }
  }

  float bsum[4];
#pragma unroll
  for (int nt = 0; nt < 4; ++nt) bsum[nt] = b1[nhalf * 64 + nt * 16 + lane15];
#pragma unroll
  for (int mt = 0; mt < 4; ++mt) {
    int rb = bm + mhalf * 64 + mt * 16 + quad * 4;
#pragma unroll
    for (int r = 0; r < 4; ++r) {
      int p = rb + r;
      if (p < PAIRS) {
#pragma unroll
        for (int nt = 0; nt < 4; ++nt) {
          float v = fmaxf(acc[mt][nt][r] + bsum[nt], 0.f);
          z1[(size_t)p * 128 + nhalf * 64 + nt * 16 + lane15] = f2bf(v);
        }
      }
    }
  }
}

// ---------------- z2 GEMM with fused logits --------------------------------
// logits[p] = relu(z1[p,:] @ W2 + b2) @ W3 + b3; BM=128, BN=N=128, K=128
__global__ __launch_bounds__(256) void gemm_logits_kernel(
    const unsigned short* __restrict__ z1, const unsigned short* __restrict__ W2t,
    const float* __restrict__ b2, const float* __restrict__ W3,
    const float* __restrict__ b3, float* __restrict__ out) {
  __shared__ __attribute__((aligned(16))) unsigned short As[128 * 32];
  __shared__ __attribute__((aligned(16))) unsigned short Bs[128 * 32];
  __shared__ float red[2][128];
  const int tid = threadIdx.x;
  const int wv = tid >> 6, ln = tid & 63;
  const int lane15 = ln & 15, quad = ln >> 4;
  const int mhalf = wv >> 1, nhalf = wv & 1;
  const int bm = blockIdx.x * 128;
  f32x4 acc[4][4] = {};

  for (int k0 = 0; k0 < 128; k0 += 32) {
    __syncthreads();
#pragma unroll
    for (int q = 0; q < 2; ++q) {
      int L = (q * 4 + wv) * 64 + ln;
      int r = L >> 2, ck = (L & 3) * 8;
      int gr = bm + r;
      if (gr > PAIRS - 1) gr = PAIRS - 1;
      glds16(z1 + (size_t)gr * 128 + k0 + ck, As + (size_t)(q * 4 + wv) * 512);
      glds16(W2t + (size_t)r * 128 + k0 + ck, Bs + (size_t)(q * 4 + wv) * 512);
    }
    __syncthreads();
    short8 af[4], bfr[4];
#pragma unroll
    for (int t = 0; t < 4; ++t) {
      af[t] = *(const short8*)&As[(mhalf * 64 + t * 16 + lane15) * 32 + quad * 8];
      bfr[t] = *(const short8*)&Bs[(nhalf * 64 + t * 16 + lane15) * 32 + quad * 8];
    }
#pragma unroll
    for (int mt = 0; mt < 4; ++mt)
#pragma unroll
      for (int nt = 0; nt < 4; ++nt)
        acc[mt][nt] = __builtin_amdgcn_mfma_f32_16x16x32_bf16(af[mt], bfr[nt],
                                                              acc[mt][nt], 0, 0, 0);
  }

  float bsum[4], w3v[4];
#pragma unroll
  for (int nt = 0; nt < 4; ++nt) {
    int col = nhalf * 64 + nt * 16 + lane15;
    bsum[nt] = b2[col];
    w3v[nt] = W3[col];
  }
  float p[4][4];
#pragma unroll
  for (int mt = 0; mt < 4; ++mt)
#pragma unroll
    for (int r = 0; r < 4; ++r) {
      float s = 0.f;
#pragma unroll
      for (int nt = 0; nt < 4; ++nt)
        s += fmaxf(acc[mt][nt][r] + bsum[nt], 0.f) * w3v[nt];
      p[mt][r] = s;
    }
#pragma unroll
  for (int st = 1; st < 16; st <<= 1)
#pragma unroll
    for (int mt = 0; mt < 4; ++mt)
#pragma unroll
      for (int r = 0; r < 4; ++r) p[mt][r] += __shfl_xor(p[mt][r], st, 64);
  if (lane15 == 0) {
#pragma unroll
    for (int mt = 0; mt < 4; ++mt)
#pragma unroll
      for (int r = 0; r < 4; ++r)
        red[nhalf][mhalf * 64 + mt * 16 + quad * 4 + r] = p[mt][r];
  }
  __syncthreads();
  if (tid < 128) {
    int prow = bm + tid;
    if (prow < PAIRS) out[prow] = red[0][tid] + red[1][tid] + b3[0];
  }
}

// ---------------- graph aggregate ----------------

__global__ __launch_bounds__(256) void aggregate_kernel(
    const unsigned short* __restrict__ h, const int* __restrict__ row_start,
    const int* __restrict__ csr, const float* __restrict__ degf,
    unsigned short* __restrict__ mean) {
  int wid = threadIdx.x >> 6, lane = threadIdx.x & 63;
  int n = blockIdx.x * 4 + wid;
  if (n >= NODES) return;
  int rs = row_start[n], re = row_start[n + 1];
  float a0 = 0.f, a1 = 0.f, a2 = 0.f, a3 = 0.f;
  int e = rs;
  for (; e + 2 <= re; e += 2) {
    int s0 = csr[e], s1 = csr[e + 1];
    ushort4 v0 = *(const ushort4*)(h + (size_t)s0 * 256 + lane * 4);
    ushort4 v1 = *(const ushort4*)(h + (size_t)s1 * 256 + lane * 4);
    a0 += bf2f(v0.x) + bf2f(v1.x);
    a1 += bf2f(v0.y) + bf2f(v1.y);
    a2 += bf2f(v0.z) + bf2f(v1.z);
    a3 += bf2f(v0.w) + bf2f(v1.w);
  }
  if (e < re) {
    ushort4 v0 = *(const ushort4*)(h + (size_t)csr[e] * 256 + lane * 4);
    a0 += bf2f(v0.x); a1 += bf2f(v0.y); a2 += bf2f(v0.z); a3 += bf2f(v0.w);
  }
  float inv = 1.0f / degf[n];
  ushort4 o = {f2bf(a0 * inv), f2bf(a1 * inv), f2bf(a2 * inv), f2bf(a3 * inv)};
  *(ushort4*)(mean + (size_t)n * 256 + lane * 4) = o;
}

// ---------------- host ----------------

extern "C" void kernel_launch(void* const* d_in, const int* in_sizes, int n_in,
                              void* d_out, int out_size, void* d_ws, size_t ws_size,
                              hipStream_t stream) {
  const float* X       = (const float*)d_in[0];
  const int*   edge    = (const int*)d_in[1];
  const int*   i_idx   = (const int*)d_in[2];
  const int*   j_idx   = (const int*)d_in[3];
  const float* W_in    = (const float*)d_in[4];
  const float* b_in    = (const float*)d_in[5];
  const float* Ws_self = (const float*)d_in[6];
  const float* bs_self = (const float*)d_in[7];
  const float* Ws_nei  = (const float*)d_in[8];
  const float* bs_nei  = (const float*)d_in[9];
  const float* gammas  = (const float*)d_in[10];
  const float* betas   = (const float*)d_in[11];
  const float* W1      = (const float*)d_in[12];
  const float* b1      = (const float*)d_in[13];
  const float* W2      = (const float*)d_in[14];
  const float* b2      = (const float*)d_in[15];
  const float* W3      = (const float*)d_in[16];
  const float* b3      = (const float*)d_in[17];

  char* w = (char*)d_ws;
  size_t off = 0;
  auto alloc = [&](size_t bytes) {
    char* p = w + off;
    off += (bytes + 255) & ~(size_t)255;
    return p;
  };
  unsigned short* hA   = (unsigned short*)alloc((size_t)NODES * 256 * 2);  // 25.6MB
  unsigned short* hB   = (unsigned short*)alloc((size_t)NODES * 256 * 2);
  unsigned short* mean = (unsigned short*)alloc((size_t)NODES * 256 * 2);
  unsigned short* Hb   = (unsigned short*)alloc((size_t)NODES * 256 * 2);
  float* degf     = (float*)alloc((size_t)NODES * 4);
  int* cnt        = (int*)alloc((size_t)2 * NODES * 4);
  int* cursor     = cnt + NODES;
  int* row_start  = (int*)alloc((size_t)(NODES + 1) * 4);
  int* csr        = (int*)alloc((size_t)EDGES * 4);
  unsigned short* WinT   = (unsigned short*)alloc((size_t)480 * 256 * 2);
  unsigned short* WselfT = (unsigned short*)alloc((size_t)3 * 256 * 256 * 2);
  unsigned short* WneiT  = (unsigned short*)alloc((size_t)3 * 256 * 256 * 2);
  unsigned short* W1T    = (unsigned short*)alloc((size_t)512 * 128 * 2);
  unsigned short* W2T    = (unsigned short*)alloc((size_t)128 * 128 * 2);
  unsigned short* Xb     = (unsigned short*)alloc((size_t)NODES * 480 * 2);  // 48MB
  unsigned short* z1 = hA;  // 51.2MB over hA+hB (both dead after layer 3)

  const int* src = edge;
  const int* dst = edge + EDGES;
  float* Hout   = (float*)d_out;
  float* logits = (float*)d_out + (size_t)NODES * 256;

  // conversions
  convx_kernel<<<(NODES * 480 / 4 + 255) / 256, 256, 0, stream>>>(X, Xb, NODES * 480 / 4);
  tconv_kernel<<<dim3(8, 15, 1), 256, 0, stream>>>(W_in, WinT, 480, 256);
  tconv_kernel<<<dim3(8, 8, 3), 256, 0, stream>>>(Ws_self, WselfT, 256, 256);
  tconv_kernel<<<dim3(8, 8, 3), 256, 0, stream>>>(Ws_nei, WneiT, 256, 256);
  tconv_kernel<<<dim3(4, 16, 1), 256, 0, stream>>>(W1, W1T, 512, 128);
  tconv_kernel<<<dim3(4, 4, 1), 256, 0, stream>>>(W2, W2T, 128, 128);

  // CSR build
  zero_ints_kernel<<<(2 * NODES + 255) / 256, 256, 0, stream>>>(cnt, 2 * NODES);
  count_deg_kernel<<<(EDGES + 255) / 256, 256, 0, stream>>>(dst, cnt);
  scan_kernel<<<1, 1024, 0, stream>>>(cnt, row_start, degf);
  fill_csr_kernel<<<(EDGES + 255) / 256, 256, 0, stream>>>(src, dst, row_start, cursor, csr);

  // encoder: hA = relu(Xb @ W_in + b_in)
  mfma_fused<0, 0><<<782, 256, 0, stream>>>(Xb, WinT, nullptr, nullptr, b_in, nullptr,
                                            nullptr, nullptr, hA, nullptr, NODES, 480);

  unsigned short* hcur = hA;
  unsigned short* hnext = hB;
  for (int l = 0; l < 3; ++l) {
    aggregate_kernel<<<NODES / 4, 256, 0, stream>>>(hcur, row_start, csr, degf, mean);
    if (l < 2) {
      mfma_fused<1, 1><<<782, 256, 0, stream>>>(
          hcur, WselfT + (size_t)l * 65536, mean, WneiT + (size_t)l * 65536,
          bs_self + l * 256, bs_nei + l * 256, gammas + l * 256, betas + l * 256,
          hnext, nullptr, NODES, 256);
      unsigned short* t = hcur; hcur = hnext; hnext = t;
    } else {
      mfma_fused<1, 2><<<782, 256, 0, stream>>>(
          hcur, WselfT + (size_t)l * 65536, mean, WneiT + (size_t)l * 65536,
          bs_self + l * 256, bs_nei + l * 256, gammas + l * 256, betas + l * 256,
          Hb, Hout, NODES, 256);
    }
  }

  // edge head
  feat_mfma_kernel<<<(PAIRS + 127) / 128, 256, 0, stream>>>(Hb, i_idx, j_idx, W1T, b1, z1);
  gemm_logits_kernel<<<(PAIRS + 127) / 128, 256, 0, stream>>>(z1, W2T, b2, W3, b3, logits);
}

// Round 4
// 567.009 us; speedup vs baseline: 2.9006x; 1.1683x over previous
//
#include <hip/hip_runtime.h>

// ---------------------------------------------------------------------------
// R3: (a) single-block scan (92us, serial) -> 3-kernel hierarchical scan;
//     (b) convx fused into encoder GEMM (fp32 A staged via VGPR convert);
//     (c) cnt/cursor zeroed with hipMemsetAsync.
// Carried from R2: fused LN / L2norm / logits epilogues, single-read feat.
// ---------------------------------------------------------------------------

#define NODES 50000
#define EDGES 300000
#define PAIRS 200000
#define SCAN_BLK 49  // ceil(NODES/1024)

typedef __attribute__((ext_vector_type(8))) short short8;
typedef __attribute__((ext_vector_type(4))) float f32x4;

__device__ __forceinline__ unsigned short f2bf(float f) {
  unsigned int u = __float_as_uint(f);
  u += 0x7fff + ((u >> 16) & 1);
  return (unsigned short)(u >> 16);
}
__device__ __forceinline__ float bf2f(unsigned short h) {
  return __uint_as_float(((unsigned int)h) << 16);
}

__device__ __forceinline__ void glds16(const void* g, void* l) {
  __builtin_amdgcn_global_load_lds(
      (const __attribute__((address_space(1))) unsigned int*)g,
      (__attribute__((address_space(3))) unsigned int*)l, 16, 0, 0);
}

// ---------------- CSR build ----------------

__global__ __launch_bounds__(256) void count_deg_kernel(const int* __restrict__ dst,
                                                        int* __restrict__ cnt) {
  int e = blockIdx.x * 256 + threadIdx.x;
  if (e < EDGES) atomicAdd(&cnt[dst[e]], 1);
}

// pass A: block b reduces counts of nodes [b*1024, b*1024+1024)
__global__ __launch_bounds__(256) void blocksum_kernel(const int* __restrict__ cnt,
                                                       int* __restrict__ bsum) {
  int base = blockIdx.x * 1024 + threadIdx.x * 4;
  int s = 0;
  if (base + 3 < NODES) {
    int4 v = *(const int4*)(cnt + base);
    s = v.x + v.y + v.z + v.w;
  } else {
#pragma unroll
    for (int k = 0; k < 4; ++k)
      if (base + k < NODES) s += cnt[base + k];
  }
#pragma unroll
  for (int off = 32; off; off >>= 1) s += __shfl_down(s, off);
  __shared__ int ws[4];
  if ((threadIdx.x & 63) == 0) ws[threadIdx.x >> 6] = s;
  __syncthreads();
  if (threadIdx.x == 0) bsum[blockIdx.x] = ws[0] + ws[1] + ws[2] + ws[3];
}

// pass B: exclusive scan of SCAN_BLK block sums (single wave)
__global__ __launch_bounds__(64) void scan_bsum_kernel(const int* __restrict__ bsum,
                                                       int* __restrict__ boff) {
  int lane = threadIdx.x;
  int v = (lane < SCAN_BLK) ? bsum[lane] : 0;
  int incl = v;
#pragma unroll
  for (int off = 1; off < 64; off <<= 1) {
    int t = __shfl_up(incl, off);
    if (lane >= off) incl += t;
  }
  if (lane < SCAN_BLK) boff[lane] = incl - v;
}

// pass C: per-block re-scan + offset -> row_start, degf
__global__ __launch_bounds__(256) void scan_final_kernel(const int* __restrict__ cnt,
                                                         const int* __restrict__ boff,
                                                         int* __restrict__ row_start,
                                                         float* __restrict__ degf) {
  int base = blockIdx.x * 1024 + threadIdx.x * 4;
  int c[4] = {0, 0, 0, 0};
  if (base + 3 < NODES) {
    int4 v = *(const int4*)(cnt + base);
    c[0] = v.x; c[1] = v.y; c[2] = v.z; c[3] = v.w;
  } else {
#pragma unroll
    for (int k = 0; k < 4; ++k)
      if (base + k < NODES) c[k] = cnt[base + k];
  }
  int s = c[0] + c[1] + c[2] + c[3];
  int lane = threadIdx.x & 63, wv = threadIdx.x >> 6;
  int incl = s;
#pragma unroll
  for (int off = 1; off < 64; off <<= 1) {
    int t = __shfl_up(incl, off);
    if (lane >= off) incl += t;
  }
  __shared__ int wsum[4];
  if (lane == 63) wsum[wv] = incl;
  __syncthreads();
  int wbase = 0;
  for (int k = 0; k < wv; ++k) wbase += wsum[k];
  int rs = boff[blockIdx.x] + wbase + incl - s;
#pragma unroll
  for (int k = 0; k < 4; ++k) {
    int i = base + k;
    if (i < NODES) {
      row_start[i] = rs;
      degf[i] = (float)(c[k] > 0 ? c[k] : 1);
      rs += c[k];
    }
  }
  if (blockIdx.x == 0 && threadIdx.x == 0) row_start[NODES] = EDGES;
}

__global__ __launch_bounds__(256) void fill_csr_kernel(const int* __restrict__ src,
                                                       const int* __restrict__ dst,
                                                       const int* __restrict__ row_start,
                                                       int* __restrict__ cursor,
                                                       int* __restrict__ csr) {
  int e = blockIdx.x * 256 + threadIdx.x;
  if (e < EDGES) {
    int d = dst[e];
    int pos = atomicAdd(&cursor[d], 1);
    csr[row_start[d] + pos] = src[e];
  }
}

// ---------------- weight transpose+convert ----------------

__global__ __launch_bounds__(256) void tconv_kernel(const float* __restrict__ in,
                                                    unsigned short* __restrict__ out,
                                                    int R, int C) {
  const float* inb = in + (size_t)blockIdx.z * R * C;
  unsigned short* outb = out + (size_t)blockIdx.z * R * C;
  __shared__ float t[32][33];
  int bx = blockIdx.x * 32, by = blockIdx.y * 32;
  int tx = threadIdx.x & 31, ty = threadIdx.x >> 5;
#pragma unroll
  for (int i = ty; i < 32; i += 8) t[i][tx] = inb[(size_t)(by + i) * C + bx + tx];
  __syncthreads();
#pragma unroll
  for (int i = ty; i < 32; i += 8)
    outb[(size_t)(bx + i) * R + by + tx] = f2bf(t[tx][i]);
}

// ---------------- fused MFMA GEMM, N=256, BM=64, full rows per block -------
// F32A: A read as fp32 with in-register bf16 convert (encoder; K=480)
// EPI: 0 = relu->bf16; 1 = relu+LN->bf16; 2 = relu+LN+L2norm->f32+bf16
template <int DUAL, int EPI, int F32A>
__global__ __launch_bounds__(256) void mfma_fused(
    const unsigned short* __restrict__ A, const float* __restrict__ Af,
    const unsigned short* __restrict__ Bt,
    const unsigned short* __restrict__ A2, const unsigned short* __restrict__ B2t,
    const float* __restrict__ bias1, const float* __restrict__ bias2,
    const float* __restrict__ gamma, const float* __restrict__ beta,
    unsigned short* __restrict__ Cb, float* __restrict__ Cf, int M, int K) {
  __shared__ __attribute__((aligned(16))) unsigned short sm[320 * 32];  // A:64, B:256
  __shared__ float red1[4][64], red2[4][64];
  __shared__ float mu_s[64], rs_s[64];
  const int tid = threadIdx.x;
  const int wv = tid >> 6, ln = tid & 63;
  const int lane15 = ln & 15, quad = ln >> 4;
  const int bm = blockIdx.x * 64;
  unsigned short* Bsm = sm + 64 * 32;
  f32x4 acc[4][4] = {};

  for (int pass = 0; pass <= DUAL; ++pass) {
    const unsigned short* __restrict__ Ap = pass ? A2 : A;
    const unsigned short* __restrict__ Bp = pass ? B2t : Bt;
    for (int k0 = 0; k0 < K; k0 += 32) {
      __syncthreads();
      if (F32A) {
        // A: fp32 -> bf16 in VGPRs, ds_write 16B
        int r = tid >> 2, ks = (tid & 3) * 8;
        int gr = bm + r;
        if (gr > M - 1) gr = M - 1;
        const float* ap = Af + (size_t)gr * K + k0 + ks;
        float4 f0 = *(const float4*)ap;
        float4 f1 = *(const float4*)(ap + 4);
        __attribute__((aligned(16))) unsigned short o[8] = {
            f2bf(f0.x), f2bf(f0.y), f2bf(f0.z), f2bf(f0.w),
            f2bf(f1.x), f2bf(f1.y), f2bf(f1.z), f2bf(f1.w)};
        *(short8*)&sm[r * 32 + ks] = *(short8*)&o[0];
#pragma unroll
        for (int q = 1; q < 5; ++q) {
          int L = q * 256 + tid;
          int rr = L >> 2, ck = (L & 3) * 8;
          glds16(Bp + (size_t)(rr - 64) * K + k0 + ck,
                 sm + (size_t)(q * 256 + (tid & 192)) * 8);
        }
      } else {
#pragma unroll
        for (int q = 0; q < 5; ++q) {
          int L = q * 256 + tid;
          int r = L >> 2, ck = (L & 3) * 8;
          const unsigned short* gp;
          if (r < 64) {
            int gr = bm + r;
            if (gr > M - 1) gr = M - 1;
            gp = Ap + (size_t)gr * K + k0 + ck;
          } else {
            gp = Bp + (size_t)(r - 64) * K + k0 + ck;
          }
          glds16(gp, sm + (size_t)(q * 256 + (tid & 192)) * 8);
        }
      }
      __syncthreads();
      short8 af[4], bfr[4];
#pragma unroll
      for (int t = 0; t < 4; ++t) {
        af[t] = *(const short8*)&sm[(t * 16 + lane15) * 32 + quad * 8];
        bfr[t] = *(const short8*)&Bsm[(wv * 64 + t * 16 + lane15) * 32 + quad * 8];
      }
#pragma unroll
      for (int mt = 0; mt < 4; ++mt)
#pragma unroll
        for (int nt = 0; nt < 4; ++nt)
          acc[mt][nt] = __builtin_amdgcn_mfma_f32_16x16x32_bf16(af[mt], bfr[nt],
                                                                acc[mt][nt], 0, 0, 0);
    }
  }

  // epilogue
  float bsum[4];
#pragma unroll
  for (int nt = 0; nt < 4; ++nt) {
    int col = wv * 64 + nt * 16 + lane15;
    bsum[nt] = bias1[col] + (DUAL ? bias2[col] : 0.f);
  }
  float vv[4][4][4];
#pragma unroll
  for (int mt = 0; mt < 4; ++mt)
#pragma unroll
    for (int nt = 0; nt < 4; ++nt)
#pragma unroll
      for (int r = 0; r < 4; ++r)
        vv[mt][nt][r] = fmaxf(acc[mt][nt][r] + bsum[nt], 0.f);

  if (EPI == 0) {
#pragma unroll
    for (int mt = 0; mt < 4; ++mt)
#pragma unroll
      for (int r = 0; r < 4; ++r) {
        int row = bm + mt * 16 + quad * 4 + r;
        if (row < M) {
#pragma unroll
          for (int nt = 0; nt < 4; ++nt)
            Cb[(size_t)row * 256 + wv * 64 + nt * 16 + lane15] = f2bf(vv[mt][nt][r]);
        }
      }
    return;
  }

  // ---- LayerNorm over the full 256-col row ----
  float s1[4][4], s2[4][4];
#pragma unroll
  for (int mt = 0; mt < 4; ++mt)
#pragma unroll
    for (int r = 0; r < 4; ++r) {
      float a = 0.f, b = 0.f;
#pragma unroll
      for (int nt = 0; nt < 4; ++nt) {
        a += vv[mt][nt][r];
        b += vv[mt][nt][r] * vv[mt][nt][r];
      }
      s1[mt][r] = a;
      s2[mt][r] = b;
    }
#pragma unroll
  for (int st = 1; st < 16; st <<= 1)
#pragma unroll
    for (int mt = 0; mt < 4; ++mt)
#pragma unroll
      for (int r = 0; r < 4; ++r) {
        s1[mt][r] += __shfl_xor(s1[mt][r], st, 64);
        s2[mt][r] += __shfl_xor(s2[mt][r], st, 64);
      }
  if (lane15 == 0) {
#pragma unroll
    for (int mt = 0; mt < 4; ++mt)
#pragma unroll
      for (int r = 0; r < 4; ++r) {
        red1[wv][mt * 16 + quad * 4 + r] = s1[mt][r];
        red2[wv][mt * 16 + quad * 4 + r] = s2[mt][r];
      }
  }
  __syncthreads();
  if (tid < 64) {
    float a = red1[0][tid] + red1[1][tid] + red1[2][tid] + red1[3][tid];
    float b = red2[0][tid] + red2[1][tid] + red2[2][tid] + red2[3][tid];
    float mu = a * (1.f / 256.f);
    float var = fmaxf(b * (1.f / 256.f) - mu * mu, 0.f);
    mu_s[tid] = mu;
    rs_s[tid] = rsqrtf(var + 1e-5f);
  }
  __syncthreads();
  float gg[4], bb[4];
#pragma unroll
  for (int nt = 0; nt < 4; ++nt) {
    int col = wv * 64 + nt * 16 + lane15;
    gg[nt] = gamma[col];
    bb[nt] = beta[col];
  }
#pragma unroll
  for (int mt = 0; mt < 4; ++mt)
#pragma unroll
    for (int r = 0; r < 4; ++r) {
      int rowl = mt * 16 + quad * 4 + r;
      float mu = mu_s[rowl], rstd = rs_s[rowl];
#pragma unroll
      for (int nt = 0; nt < 4; ++nt)
        vv[mt][nt][r] = (vv[mt][nt][r] - mu) * rstd * gg[nt] + bb[nt];
    }

  if (EPI == 1) {
#pragma unroll
    for (int mt = 0; mt < 4; ++mt)
#pragma unroll
      for (int r = 0; r < 4; ++r) {
        int row = bm + mt * 16 + quad * 4 + r;
        if (row < M) {
#pragma unroll
          for (int nt = 0; nt < 4; ++nt)
            Cb[(size_t)row * 256 + wv * 64 + nt * 16 + lane15] = f2bf(vv[mt][nt][r]);
        }
      }
    return;
  }

  // ---- EPI==2: L2 normalize; store f32 Cf and bf16 Cb ----
  __syncthreads();
#pragma unroll
  for (int mt = 0; mt < 4; ++mt)
#pragma unroll
    for (int r = 0; r < 4; ++r) {
      float b = 0.f;
#pragma unroll
      for (int nt = 0; nt < 4; ++nt) b += vv[mt][nt][r] * vv[mt][nt][r];
      s2[mt][r] = b;
    }
#pragma unroll
  for (int st = 1; st < 16; st <<= 1)
#pragma unroll
    for (int mt = 0; mt < 4; ++mt)
#pragma unroll
      for (int r = 0; r < 4; ++r) s2[mt][r] += __shfl_xor(s2[mt][r], st, 64);
  if (lane15 == 0) {
#pragma unroll
    for (int mt = 0; mt < 4; ++mt)
#pragma unroll
      for (int r = 0; r < 4; ++r) red1[wv][mt * 16 + quad * 4 + r] = s2[mt][r];
  }
  __syncthreads();
  if (tid < 64) {
    float b = red1[0][tid] + red1[1][tid] + red1[2][tid] + red1[3][tid];
    mu_s[tid] = 1.f / fmaxf(sqrtf(b), 1e-12f);
  }
  __syncthreads();
#pragma unroll
  for (int mt = 0; mt < 4; ++mt)
#pragma unroll
    for (int r = 0; r < 4; ++r) {
      int rowl = mt * 16 + quad * 4 + r;
      int row = bm + rowl;
      float inv = mu_s[rowl];
      if (row < M) {
#pragma unroll
        for (int nt = 0; nt < 4; ++nt) {
          float y = vv[mt][nt][r] * inv;
          size_t idx = (size_t)row * 256 + wv * 64 + nt * 16 + lane15;
          Cf[idx] = y;
          Cb[idx] = f2bf(y);
        }
      }
    }
}

// ---------------- feat GEMM: single-read dual A-tile -----------------------
__global__ __launch_bounds__(256) void feat_mfma_kernel(
    const unsigned short* __restrict__ Hb, const int* __restrict__ i_idx,
    const int* __restrict__ j_idx, const unsigned short* __restrict__ W1t,
    const float* __restrict__ b1, unsigned short* __restrict__ z1) {
  __shared__ __attribute__((aligned(16))) unsigned short Aabs[128 * 32];
  __shared__ __attribute__((aligned(16))) unsigned short Aprd[128 * 32];
  __shared__ __attribute__((aligned(16))) unsigned short Blo[128 * 32];
  __shared__ __attribute__((aligned(16))) unsigned short Bhi[128 * 32];
  __shared__ int ii[128], jj[128];
  const int tid = threadIdx.x;
  const int wv = tid >> 6, ln = tid & 63;
  const int lane15 = ln & 15, quad = ln >> 4;
  const int mhalf = wv >> 1, nhalf = wv & 1;
  const int bm = blockIdx.x * 128;
  if (tid < 128) {
    int p = bm + tid;
    if (p > PAIRS - 1) p = PAIRS - 1;
    ii[tid] = i_idx[p];
    jj[tid] = j_idx[p];
  }
  f32x4 acc[4][4] = {};
  const int ar = tid >> 1;
  const int ak = (tid & 1) * 16;

  for (int k0 = 0; k0 < 256; k0 += 32) {
    __syncthreads();
#pragma unroll
    for (int q = 0; q < 2; ++q) {
      int L = q * 256 + tid;
      int r = L >> 2, ck = (L & 3) * 8;
      glds16(W1t + (size_t)r * 512 + k0 + ck,
             Blo + (size_t)(q * 256 + (tid & 192)) * 8);
      glds16(W1t + (size_t)r * 512 + 256 + k0 + ck,
             Bhi + (size_t)(q * 256 + (tid & 192)) * 8);
    }
    {
      int kk = k0 + ak;
      const unsigned short* hi = Hb + (size_t)ii[ar] * 256 + kk;
      const unsigned short* hj = Hb + (size_t)jj[ar] * 256 + kk;
      union U { uint4 v; unsigned short s[8]; };
      U a0, a1, c0, c1;
      a0.v = *(const uint4*)(hi);
      a1.v = *(const uint4*)(hi + 8);
      c0.v = *(const uint4*)(hj);
      c1.v = *(const uint4*)(hj + 8);
      __attribute__((aligned(16))) unsigned short oabs[16], oprd[16];
#pragma unroll
      for (int e = 0; e < 8; ++e) {
        float x = bf2f(a0.s[e]), y = bf2f(c0.s[e]);
        oabs[e] = f2bf(fabsf(x - y));
        oprd[e] = f2bf(x * y);
      }
#pragma unroll
      for (int e = 0; e < 8; ++e) {
        float x = bf2f(a1.s[e]), y = bf2f(c1.s[e]);
        oabs[8 + e] = f2bf(fabsf(x - y));
        oprd[8 + e] = f2bf(x * y);
      }
      *(short8*)&Aabs[ar * 32 + ak] = *(short8*)&oabs[0];
      *(short8*)&Aabs[ar * 32 + ak + 8] = *(short8*)&oabs[8];
      *(short8*)&Aprd[ar * 32 + ak] = *(short8*)&oprd[0];
      *(short8*)&Aprd[ar * 32 + ak + 8] = *(short8*)&oprd[8];
    }
    __syncthreads();
    short8 aA[4], aP[4], bL[4], bH[4];
#pragma unroll
    for (int t = 0; t < 4; ++t) {
      int arow = (mhalf * 64 + t * 16 + lane15) * 32 + quad * 8;
      int brow = (nhalf * 64 + t * 16 + lane15) * 32 + quad * 8;
      aA[t] = *(const short8*)&Aabs[arow];
      aP[t] = *(const short8*)&Aprd[arow];
      bL[t] = *(const short8*)&Blo[brow];
      bH[t] = *(const short8*)&Bhi[brow];
    }
#pragma unroll
    for (int mt = 0; mt < 4; ++mt)
#pragma unroll
      for (int nt = 0; nt < 4; ++nt) {
        acc[mt][nt] = __builtin_amdgcn_mfma_f32_16x16x32_bf16(aA[mt], bL[nt],
                                                              acc[mt][nt], 0, 0, 0);
        acc[mt][nt] = __builtin_amdgcn_mfma_f32_16x16x32_bf16(aP[mt], bH[nt],
                                                              acc[mt][nt], 0, 0, 0);
      }
  }

  float bsum[4];
#pragma unroll
  for (int nt = 0; nt < 4; ++nt) bsum[nt] = b1[nhalf * 64 + nt * 16 + lane15];
#pragma unroll
  for (int mt = 0; mt < 4; ++mt) {
    int rb = bm + mhalf * 64 + mt * 16 + quad * 4;
#pragma unroll
    for (int r = 0; r < 4; ++r) {
      int p = rb + r;
      if (p < PAIRS) {
#pragma unroll
        for (int nt = 0; nt < 4; ++nt) {
          float v = fmaxf(acc[mt][nt][r] + bsum[nt], 0.f);
          z1[(size_t)p * 128 + nhalf * 64 + nt * 16 + lane15] = f2bf(v);
        }
      }
    }
  }
}

// ---------------- z2 GEMM with fused logits --------------------------------
__global__ __launch_bounds__(256) void gemm_logits_kernel(
    const unsigned short* __restrict__ z1, const unsigned short* __restrict__ W2t,
    const float* __restrict__ b2, const float* __restrict__ W3,
    const float* __restrict__ b3, float* __restrict__ out) {
  __shared__ __attribute__((aligned(16))) unsigned short As[128 * 32];
  __shared__ __attribute__((aligned(16))) unsigned short Bs[128 * 32];
  __shared__ float red[2][128];
  const int tid = threadIdx.x;
  const int wv = tid >> 6, ln = tid & 63;
  const int lane15 = ln & 15, quad = ln >> 4;
  const int mhalf = wv >> 1, nhalf = wv & 1;
  const int bm = blockIdx.x * 128;
  f32x4 acc[4][4] = {};

  for (int k0 = 0; k0 < 128; k0 += 32) {
    __syncthreads();
#pragma unroll
    for (int q = 0; q < 2; ++q) {
      int L = (q * 4 + wv) * 64 + ln;
      int r = L >> 2, ck = (L & 3) * 8;
      int gr = bm + r;
      if (gr > PAIRS - 1) gr = PAIRS - 1;
      glds16(z1 + (size_t)gr * 128 + k0 + ck, As + (size_t)(q * 4 + wv) * 512);
      glds16(W2t + (size_t)r * 128 + k0 + ck, Bs + (size_t)(q * 4 + wv) * 512);
    }
    __syncthreads();
    short8 af[4], bfr[4];
#pragma unroll
    for (int t = 0; t < 4; ++t) {
      af[t] = *(const short8*)&As[(mhalf * 64 + t * 16 + lane15) * 32 + quad * 8];
      bfr[t] = *(const short8*)&Bs[(nhalf * 64 + t * 16 + lane15) * 32 + quad * 8];
    }
#pragma unroll
    for (int mt = 0; mt < 4; ++mt)
#pragma unroll
      for (int nt = 0; nt < 4; ++nt)
        acc[mt][nt] = __builtin_amdgcn_mfma_f32_16x16x32_bf16(af[mt], bfr[nt],
                                                              acc[mt][nt], 0, 0, 0);
  }

  float bsum[4], w3v[4];
#pragma unroll
  for (int nt = 0; nt < 4; ++nt) {
    int col = nhalf * 64 + nt * 16 + lane15;
    bsum[nt] = b2[col];
    w3v[nt] = W3[col];
  }
  float p[4][4];
#pragma unroll
  for (int mt = 0; mt < 4; ++mt)
#pragma unroll
    for (int r = 0; r < 4; ++r) {
      float s = 0.f;
#pragma unroll
      for (int nt = 0; nt < 4; ++nt)
        s += fmaxf(acc[mt][nt][r] + bsum[nt], 0.f) * w3v[nt];
      p[mt][r] = s;
    }
#pragma unroll
  for (int st = 1; st < 16; st <<= 1)
#pragma unroll
    for (int mt = 0; mt < 4; ++mt)
#pragma unroll
      for (int r = 0; r < 4; ++r) p[mt][r] += __shfl_xor(p[mt][r], st, 64);
  if (lane15 == 0) {
#pragma unroll
    for (int mt = 0; mt < 4; ++mt)
#pragma unroll
      for (int r = 0; r < 4; ++r)
        red[nhalf][mhalf * 64 + mt * 16 + quad * 4 + r] = p[mt][r];
  }
  __syncthreads();
  if (tid < 128) {
    int prow = bm + tid;
    if (prow < PAIRS) out[prow] = red[0][tid] + red[1][tid] + b3[0];
  }
}

// ---------------- graph aggregate ----------------

__global__ __launch_bounds__(256) void aggregate_kernel(
    const unsigned short* __restrict__ h, const int* __restrict__ row_start,
    const int* __restrict__ csr, const float* __restrict__ degf,
    unsigned short* __restrict__ mean) {
  int wid = threadIdx.x >> 6, lane = threadIdx.x & 63;
  int n = blockIdx.x * 4 + wid;
  if (n >= NODES) return;
  int rs = row_start[n], re = row_start[n + 1];
  float a0 = 0.f, a1 = 0.f, a2 = 0.f, a3 = 0.f;
  int e = rs;
  for (; e + 2 <= re; e += 2) {
    int s0 = csr[e], s1 = csr[e + 1];
    ushort4 v0 = *(const ushort4*)(h + (size_t)s0 * 256 + lane * 4);
    ushort4 v1 = *(const ushort4*)(h + (size_t)s1 * 256 + lane * 4);
    a0 += bf2f(v0.x) + bf2f(v1.x);
    a1 += bf2f(v0.y) + bf2f(v1.y);
    a2 += bf2f(v0.z) + bf2f(v1.z);
    a3 += bf2f(v0.w) + bf2f(v1.w);
  }
  if (e < re) {
    ushort4 v0 = *(const ushort4*)(h + (size_t)csr[e] * 256 + lane * 4);
    a0 += bf2f(v0.x); a1 += bf2f(v0.y); a2 += bf2f(v0.z); a3 += bf2f(v0.w);
  }
  float inv = 1.0f / degf[n];
  ushort4 o = {f2bf(a0 * inv), f2bf(a1 * inv), f2bf(a2 * inv), f2bf(a3 * inv)};
  *(ushort4*)(mean + (size_t)n * 256 + lane * 4) = o;
}

// ---------------- host ----------------

extern "C" void kernel_launch(void* const* d_in, const int* in_sizes, int n_in,
                              void* d_out, int out_size, void* d_ws, size_t ws_size,
                              hipStream_t stream) {
  const float* X       = (const float*)d_in[0];
  const int*   edge    = (const int*)d_in[1];
  const int*   i_idx   = (const int*)d_in[2];
  const int*   j_idx   = (const int*)d_in[3];
  const float* W_in    = (const float*)d_in[4];
  const float* b_in    = (const float*)d_in[5];
  const float* Ws_self = (const float*)d_in[6];
  const float* bs_self = (const float*)d_in[7];
  const float* Ws_nei  = (const float*)d_in[8];
  const float* bs_nei  = (const float*)d_in[9];
  const float* gammas  = (const float*)d_in[10];
  const float* betas   = (const float*)d_in[11];
  const float* W1      = (const float*)d_in[12];
  const float* b1      = (const float*)d_in[13];
  const float* W2      = (const float*)d_in[14];
  const float* b2      = (const float*)d_in[15];
  const float* W3      = (const float*)d_in[16];
  const float* b3      = (const float*)d_in[17];

  char* w = (char*)d_ws;
  size_t off = 0;
  auto alloc = [&](size_t bytes) {
    char* p = w + off;
    off += (bytes + 255) & ~(size_t)255;
    return p;
  };
  unsigned short* hA   = (unsigned short*)alloc((size_t)NODES * 256 * 2);  // 25.6MB
  unsigned short* hB   = (unsigned short*)alloc((size_t)NODES * 256 * 2);
  unsigned short* mean = (unsigned short*)alloc((size_t)NODES * 256 * 2);
  unsigned short* Hb   = (unsigned short*)alloc((size_t)NODES * 256 * 2);
  float* degf     = (float*)alloc((size_t)NODES * 4);
  int* cnt        = (int*)alloc((size_t)2 * NODES * 4);
  int* cursor     = cnt + NODES;
  int* row_start  = (int*)alloc((size_t)(NODES + 1) * 4);
  int* csr        = (int*)alloc((size_t)EDGES * 4);
  int* bsum       = (int*)alloc((size_t)(SCAN_BLK + 1) * 4);
  int* boff       = (int*)alloc((size_t)(SCAN_BLK + 1) * 4);
  unsigned short* WinT   = (unsigned short*)alloc((size_t)480 * 256 * 2);
  unsigned short* WselfT = (unsigned short*)alloc((size_t)3 * 256 * 256 * 2);
  unsigned short* WneiT  = (unsigned short*)alloc((size_t)3 * 256 * 256 * 2);
  unsigned short* W1T    = (unsigned short*)alloc((size_t)512 * 128 * 2);
  unsigned short* W2T    = (unsigned short*)alloc((size_t)128 * 128 * 2);
  unsigned short* z1 = hA;  // reuse (hA/hB dead after layer 3)

  const int* src = edge;
  const int* dst = edge + EDGES;
  float* Hout   = (float*)d_out;
  float* logits = (float*)d_out + (size_t)NODES * 256;

  // weight conversions
  tconv_kernel<<<dim3(8, 15, 1), 256, 0, stream>>>(W_in, WinT, 480, 256);
  tconv_kernel<<<dim3(8, 8, 3), 256, 0, stream>>>(Ws_self, WselfT, 256, 256);
  tconv_kernel<<<dim3(8, 8, 3), 256, 0, stream>>>(Ws_nei, WneiT, 256, 256);
  tconv_kernel<<<dim3(4, 16, 1), 256, 0, stream>>>(W1, W1T, 512, 128);
  tconv_kernel<<<dim3(4, 4, 1), 256, 0, stream>>>(W2, W2T, 128, 128);

  // CSR build (hierarchical scan)
  hipMemsetAsync(cnt, 0, (size_t)2 * NODES * 4, stream);
  count_deg_kernel<<<(EDGES + 255) / 256, 256, 0, stream>>>(dst, cnt);
  blocksum_kernel<<<SCAN_BLK, 256, 0, stream>>>(cnt, bsum);
  scan_bsum_kernel<<<1, 64, 0, stream>>>(bsum, boff);
  scan_final_kernel<<<SCAN_BLK, 256, 0, stream>>>(cnt, boff, row_start, degf);
  fill_csr_kernel<<<(EDGES + 255) / 256, 256, 0, stream>>>(src, dst, row_start, cursor, csr);

  // encoder: hA = relu(X @ W_in + b_in), fp32 A staged in-kernel
  mfma_fused<0, 0, 1><<<782, 256, 0, stream>>>(
      nullptr, X, WinT, nullptr, nullptr, b_in, nullptr, nullptr, nullptr,
      hA, nullptr, NODES, 480);

  unsigned short* hcur = hA;
  unsigned short* hnext = hB;
  for (int l = 0; l < 3; ++l) {
    aggregate_kernel<<<NODES / 4, 256, 0, stream>>>(hcur, row_start, csr, degf, mean);
    if (l < 2) {
      mfma_fused<1, 1, 0><<<782, 256, 0, stream>>>(
          hcur, nullptr, WselfT + (size_t)l * 65536, mean, WneiT + (size_t)l * 65536,
          bs_self + l * 256, bs_nei + l * 256, gammas + l * 256, betas + l * 256,
          hnext, nullptr, NODES, 256);
      unsigned short* t = hcur; hcur = hnext; hnext = t;
    } else {
      mfma_fused<1, 2, 0><<<782, 256, 0, stream>>>(
          hcur, nullptr, WselfT + (size_t)l * 65536, mean, WneiT + (size_t)l * 65536,
          bs_self + l * 256, bs_nei + l * 256, gammas + l * 256, betas + l * 256,
          Hb, Hout, NODES, 256);
    }
  }

  // edge head
  feat_mfma_kernel<<<(PAIRS + 127) / 128, 256, 0, stream>>>(Hb, i_idx, j_idx, W1T, b1, z1);
  gemm_logits_kernel<<<(PAIRS + 127) / 128, 256, 0, stream>>>(z1, W2T, b2, W3, b3, logits);
}